// Round 4
// baseline (188554.663 us; speedup 1.0000x reference)
//
#include <hip/hip_runtime.h>
#include <hip/hip_bf16.h>
#include <hip/hip_cooperative_groups.h>

namespace cg = cooperative_groups;
typedef __hip_bfloat16 bf16;

#define TB 512   // threads per block in persistent kernel
#define NWG 256  // workgroups in persistent kernel

// device-scope fence around grid barrier (cross-XCD visibility of plain stores)
#define GSYNC() do{ __threadfence(); grid.sync(); __threadfence(); }while(0)

__device__ __forceinline__ float b2f(bf16 x){ return __bfloat162float(x); }
__device__ __forceinline__ float sigf(float x){ return 1.f/(1.f+expf(-x)); }
__device__ __forceinline__ float splus(float x){ return fmaxf(x,0.f)+log1pf(expf(-fabsf(x))); }

// dual-dtype loader: inputs may be float32 or bfloat16; flag chosen at runtime.
__device__ __forceinline__ float ldf(const void* p, int i, int isf32){
  return isf32 ? ((const float*)p)[i] : __bfloat162float(((const bf16*)p)[i]);
}

// ---------------- dtype detection: read emb as bf16; f32 data shows huge exponents ----------------
__global__ void k_detect(const void* __restrict__ emb, int* __restrict__ flag){
  __shared__ float mx[256];
  int tid=threadIdx.x;
  float v = fabsf(__bfloat162float(((const bf16*)emb)[tid]));
  mx[tid]=v; __syncthreads();
  for(int s=128;s>0;s>>=1){ if(tid<s) mx[tid]=fmaxf(mx[tid],mx[tid+s]); __syncthreads(); }
  if(tid==0) flag[0] = (mx[0]>1000.f) ? 1 : 0;
}

// ---------------- setup kernels ----------------

// embW[row][v] = sum_k emb[v][k] * Wi0[row][k]   (row<2048, v<256, k<512)
__global__ void k_embW(const void* __restrict__ emb, const void* __restrict__ Wi0,
                       const int* __restrict__ flags, float* __restrict__ embW){
  int f=flags[0];
  int row = blockIdx.x;              // 0..2047
  __shared__ float w[512];
  for(int k=threadIdx.x;k<512;k+=256) w[k]=ldf(Wi0,row*576+k,f);
  __syncthreads();
  int v = threadIdx.x;               // 0..255
  float acc=0.f;
  #pragma unroll 4
  for(int k=0;k<512;k++) acc += ldf(emb,v*512+k,f)*w[k];
  embW[row*256+v]=acc;
}

// W_ifT[k][v] (pad 136, f32) transpose of W_if (135x512); b_if -> f32
__global__ void k_wifT(const void* __restrict__ W_if, const void* __restrict__ b_if,
                       const int* __restrict__ flags,
                       float* __restrict__ W_ifT, float* __restrict__ b_ifF){
  int f=flags[0];
  int idx=blockIdx.x*256+threadIdx.x;
  if(idx<135*512){ int v=idx/512, k=idx-v*512; W_ifT[k*136+v]=ldf(W_if,idx,f); }
  if(idx<135) b_ifF[idx]=ldf(b_if,idx,f);
}

// Wc[v][j] = sum_d W_fc[v][d]*W_out[d][j];  bc[v] = b_fc[v] + W_fc[v,:]@b_out
__global__ void k_wc(const void* __restrict__ W_fc, const void* __restrict__ W_out,
                     const void* __restrict__ b_out, const void* __restrict__ b_fc,
                     const int* __restrict__ flags,
                     float* __restrict__ Wc, float* __restrict__ bc){
  int f=flags[0];
  int idx=blockIdx.x*256+threadIdx.x;    // 576 blocks * 256 = 147456
  int v=idx/576, j=idx-v*576;
  float acc=0.f;
  #pragma unroll 4
  for(int d=0;d<512;d++) acc += ldf(W_fc,v*512+d,f)*ldf(W_out,d*576+j,f);
  Wc[idx]=acc;
  if(j==0){
    float a=ldf(b_fc,v,f);
    for(int d=0;d<512;d++) a += ldf(W_fc,v*512+d,f)*ldf(b_out,d,f);
    bc[v]=a;
  }
}

// ---------------- persistent recurrence kernel (cooperative) ----------------
// 256 wgs x 512 threads. wg owns layer-0/1 units {2wg,2wg+1}. rg = gate*2+u,
// global gate row G = gate*512 + 2wg + u. State transposed: hT[k][b].
__global__ void __launch_bounds__(512) k_dnc(
    const int* __restrict__ tokens,
    const void* __restrict__ Wi0, const void* __restrict__ Wh0, const void* __restrict__ b0,
    const void* __restrict__ Wi1, const void* __restrict__ Wh1, const void* __restrict__ b1,
    const int* __restrict__ flags,
    const float* __restrict__ embW, const float* __restrict__ W_ifT, const float* __restrict__ b_ifF,
    float* h0T, float* h1T, float* lrT,   // mutable cross-wg state: no __restrict__
    bf16* __restrict__ cat)
{
  __shared__ float LWh0[8*512];
  __shared__ float LWi1[8*512];
  __shared__ float LWh1[8*512];
  __shared__ float LWr [8*64];
  __shared__ float Lb0[8], Lb1[8];
  __shared__ float pre0[8*64];
  __shared__ float pre1[8*64];
  __shared__ float c0s[128], c1s[128];
  __shared__ float orow[512];
  __shared__ float xis[136];
  __shared__ float xpart[3*136];
  __shared__ float s_mem[80], s_mem2[80];
  __shared__ float s_link[25], s_link2[25];
  __shared__ float s_prec[5], s_prec2[5];
  __shared__ float s_rwp[20], s_rw[20];
  __shared__ float s_wwp[5], s_ww[5], s_usage[5];
  __shared__ float s_wl[5];
  __shared__ float s_rl[20], s_fwd[20], s_bwd[20];
  __shared__ float s_wsum;

  const int wg = blockIdx.x;
  const int tid = threadIdx.x;
  const int b  = tid & 63;
  const int rg = tid >> 6;
  const int f32i = flags[0];

  for(int idx=tid; idx<8*512; idx+=TB){
    int r=idx>>9, k=idx&511;
    int G=((r>>1)<<9)+(wg<<1)+(r&1);
    LWh0[idx]=ldf(Wh0,G*512+k,f32i);
    LWi1[idx]=ldf(Wi1,G*512+k,f32i);
    LWh1[idx]=ldf(Wh1,G*512+k,f32i);
  }
  for(int idx=tid; idx<8*64; idx+=TB){
    int r=idx>>6, k=idx&63;
    int G=((r>>1)<<9)+(wg<<1)+(r&1);
    LWr[idx]=ldf(Wi0,G*576+512+k,f32i);
  }
  if(tid<8){
    int G=((tid>>1)<<9)+(wg<<1)+(tid&1);
    Lb0[tid]=ldf(b0,G,f32i); Lb1[tid]=ldf(b1,G,f32i);
  }
  if(tid<128){
    c0s[tid]=0.f; c1s[tid]=0.f;
    int u=tid>>6, bb=tid&63; int kk=(wg<<1)+u;
    h0T[kk*64+bb]=0.f;      // parity buffer 0 (read at t=0)
    h1T[kk*64+bb]=0.f;
  }
  if(wg<64){
    if(tid<64) lrT[tid*64+wg]=0.f;
    if(tid<80) s_mem[tid]=0.f;
    if(tid>=128&&tid<153) s_link[tid-128]=0.f;
    if(tid>=160&&tid<165) s_prec[tid-160]=0.f;
    if(tid>=192&&tid<212) s_rwp[tid-192]=0.f;
    if(tid>=224&&tid<229) s_wwp[tid-224]=0.f;
    if(tid>=256&&tid<261) s_usage[tid-256]=0.f;
  }
  cg::grid_group grid = cg::this_grid();
  GSYNC();

  for(int t=0;t<512;t++){
    const float* h0old = h0T + (t&1)*(512*64);
    float*       h0new = h0T + ((t+1)&1)*(512*64);
    // P1: g0 = b0 + embW[tok] + lr@Wr.T + h0@Wh0.T ; overlapped g1h = b1 + h1@Wh1.T
    {
      int tok = tokens[b*512+t];
      int G=((rg>>1)<<9)+(wg<<1)+(rg&1);
      float a0 = Lb0[rg] + embW[G*256+tok];
      float a1 = Lb1[rg];
      const float* wh0=&LWh0[rg<<9];
      const float* wh1=&LWh1[rg<<9];
      #pragma unroll 4
      for(int k=0;k<512;k++){
        a0 += h0old[(k<<6)+b]*wh0[k];
        a1 += h1T  [(k<<6)+b]*wh1[k];
      }
      const float* wr=&LWr[rg<<6];
      #pragma unroll 4
      for(int k=0;k<64;k++) a0 += lrT[(k<<6)+b]*wr[k];
      pre0[(rg<<6)+b]=a0;
      pre1[(rg<<6)+b]=a1;
    }
    __syncthreads();
    if(tid<128){
      int u=tid>>6, bb=tid&63;
      float gi=pre0[(u<<6)+bb], gf=pre0[((2+u)<<6)+bb], gg=pre0[((4+u)<<6)+bb], go=pre0[((6+u)<<6)+bb];
      float c=sigf(gf)*c0s[tid]+sigf(gi)*tanhf(gg);
      float h=sigf(go)*tanhf(c);
      c0s[tid]=c;
      h0new[((wg<<1)+u)*64+bb]=h;
    }
    GSYNC();
    // P2: g1 = g1h + h0'@Wi1.T ; LSTM1 update; out = clip(h1')
    {
      float a=pre1[(rg<<6)+b];
      const float* wi1=&LWi1[rg<<9];
      #pragma unroll 4
      for(int k=0;k<512;k++) a += h0new[(k<<6)+b]*wi1[k];
      pre0[(rg<<6)+b]=a;
    }
    __syncthreads();
    if(tid<128){
      int u=tid>>6, bb=tid&63;
      float gi=pre0[(u<<6)+bb], gf=pre0[((2+u)<<6)+bb], gg=pre0[((4+u)<<6)+bb], go=pre0[((6+u)<<6)+bb];
      float c=sigf(gf)*c1s[tid]+sigf(gi)*tanhf(gg);
      float h=sigf(go)*tanhf(c);
      c1s[tid]=c;
      int kk=(wg<<1)+u;
      h1T[kk*64+bb]=h;
      float out=fminf(fmaxf(h,-20.f),20.f);
      cat[(bb*512+t)*576+kk]=__float2bfloat16(out);
    }
    GSYNC();
    // P3: interface vector + DNC memory update (wg bb handles batch bb)
    if(wg<64){
      const int bb=wg;
      orow[tid]=fminf(fmaxf(h1T[tid*64+bb],-20.f),20.f);
      __syncthreads();
      if(tid<405){
        int q=tid/135, v=tid-q*135;
        int k0=q*171, k1=k0+171; if(k1>512)k1=512;
        float a=0.f;
        for(int k=k0;k<k1;k++) a += orow[k]*W_ifT[k*136+v];
        xpart[q*136+v]=a;
      }
      __syncthreads();
      if(tid<135) xis[tid]=b_ifF[tid]+xpart[tid]+xpart[136+tid]+xpart[272+tid];
      __syncthreads();
      if(tid<5){
        int m=tid;
        float u=s_usage[m]+(1.f-s_usage[m])*s_wwp[m];
        float psi=1.f;
        #pragma unroll
        for(int r=0;r<4;r++) psi *= 1.f - sigf(xis[117+r])*s_rwp[r*5+m];
        u*=psi;
        s_usage[m]=u;
        float nm=0.f,dt=0.f,nk=0.f;
        #pragma unroll
        for(int w=0;w<16;w++){
          float mv=s_mem[m*16+w], kv=tanhf(xis[68+w]);
          nm+=mv*mv; dt+=mv*kv; nk+=kv*kv;
        }
        float sim=dt/((sqrtf(nm)+1e-6f)*(sqrtf(nk)+1e-6f));
        s_wl[m]=sim*splus(xis[84]);
      }
      __syncthreads();
      if(tid==0){
        float mx=-1e30f;
        for(int m=0;m<5;m++) mx=fmaxf(mx,s_wl[m]);
        float e[5]; float s=0.f;
        for(int m=0;m<5;m++){ e[m]=expf(s_wl[m]-mx); s+=e[m]; }
        float u[5]; int id[5];
        for(int m=0;m<5;m++){ u[m]=1e-6f+(1.f-1e-6f)*s_usage[m]; id[m]=m; }
        for(int i=1;i<5;i++){
          float uv=u[i]; int iv=id[i]; int j=i-1;
          while(j>=0&&u[j]>uv){u[j+1]=u[j];id[j+1]=id[j];j--;}
          u[j+1]=uv; id[j+1]=iv;
        }
        float alm[5]; float prod=1.f;
        for(int i=0;i<5;i++){ alm[id[i]]=(1.f-u[i])*prod; prod*=u[i]; }
        float ag=sigf(xis[121]), wgg=sigf(xis[122]);
        float wsum=0.f;
        for(int m=0;m<5;m++){
          float wcw=e[m]/s;
          float w_=wgg*(ag*alm[m]+(1.f-ag)*wcw);
          s_ww[m]=w_; wsum+=w_;
        }
        s_wsum=wsum;
      }
      __syncthreads();
      if(tid<80){
        int m=tid>>4,w=tid&15;
        float er=sigf(xis[85+w]), wv=tanhf(xis[101+w]);
        float w_=s_ww[m];
        s_mem2[tid]=s_mem[tid]*(1.f-w_*er)+w_*wv;
      } else if(tid>=128&&tid<153){
        int q=tid-128; int i=q/5, j=q-5*i;
        s_link2[q]=(i==j)?0.f:((1.f-s_ww[i]-s_ww[j])*s_link[q]+s_ww[i]*s_prec[j]);
      } else if(tid>=160&&tid<165){
        int j=tid-160;
        s_prec2[j]=(1.f-s_wsum)*s_prec[j]+s_ww[j];
      }
      __syncthreads();
      if(tid<20){
        int r=tid/5,m=tid-5*(tid/5);
        float nm=0.f,dt=0.f,nk=0.f;
        #pragma unroll
        for(int w=0;w<16;w++){
          float mv=s_mem2[m*16+w], kv=tanhf(xis[r*16+w]);
          nm+=mv*mv; dt+=mv*kv; nk+=kv*kv;
        }
        float sim=dt/((sqrtf(nm)+1e-6f)*(sqrtf(nk)+1e-6f));
        s_rl[tid]=sim*splus(xis[64+r]);
      } else if(tid>=64&&tid<84){
        int q=tid-64; int r=q/5, i=q-5*r;
        float a=0.f;
        #pragma unroll
        for(int j=0;j<5;j++) a+=s_link2[i*5+j]*s_rwp[r*5+j];
        s_fwd[r*5+i]=a;
      } else if(tid>=96&&tid<116){
        int q=tid-96; int r=q/5, j=q-5*r;
        float a=0.f;
        #pragma unroll
        for(int i=0;i<5;i++) a+=s_link2[i*5+j]*s_rwp[r*5+i];
        s_bwd[r*5+j]=a;
      }
      __syncthreads();
      if(tid<20){
        int r=tid/5;
        float mx=-1e30f;
        for(int m=0;m<5;m++) mx=fmaxf(mx,s_rl[r*5+m]);
        float s=0.f;
        for(int m=0;m<5;m++) s+=expf(s_rl[r*5+m]-mx);
        float rcw=expf(s_rl[tid]-mx)/s;
        float q0=xis[123+3*r],q1=xis[124+3*r],q2=xis[125+3*r];
        float m3=fmaxf(q0,fmaxf(q1,q2));
        float e0=expf(q0-m3),e1=expf(q1-m3),e2=expf(q2-m3);
        float inv=1.f/(e0+e1+e2);
        s_rw[tid]=(e0*s_bwd[tid]+e1*s_fwd[tid]+e2*rcw)*inv;
      }
      __syncthreads();
      if(tid<64){
        int r=tid>>4,w=tid&15;
        float a=0.f;
        #pragma unroll
        for(int m=0;m<5;m++) a+=s_rw[r*5+m]*s_mem2[m*16+w];
        lrT[tid*64+bb]=a;
        cat[(bb*512+t)*576+512+tid]=__float2bfloat16(a);
      } else if(tid>=128&&tid<208){ s_mem [tid-128]=s_mem2 [tid-128];
      } else if(tid>=208&&tid<233){ s_link[tid-208]=s_link2[tid-208];
      } else if(tid>=240&&tid<245){ s_prec[tid-240]=s_prec2[tid-240];
      } else if(tid>=256&&tid<276){ s_rwp [tid-256]=s_rw   [tid-256];
      } else if(tid>=288&&tid<293){ s_wwp [tid-288]=s_ww   [tid-288]; }
    }
    GSYNC();
  }
}

// ---------------- final output GEMM: logits[b][v][t] = bc[v] + cat[b,t,:] . Wc[v,:] ----------------
// OUTPUT IS FLOAT32 (reference output dtype) — this was the round-2/3 failure.
__global__ void __launch_bounds__(256) k_out(const bf16* __restrict__ cat,
                                             const float* __restrict__ Wc,
                                             const float* __restrict__ bc,
                                             float* __restrict__ outp){
  int t0=blockIdx.x*64, v0=blockIdx.y*64, b=blockIdx.z;
  __shared__ float As[64][33];
  __shared__ float Bs[32][65];
  int tid=threadIdx.x;
  int ti=tid>>4, vi=tid&15;
  float acc[4][4]={};
  for(int k0=0;k0<576;k0+=32){
    for(int i=tid;i<64*32;i+=256){
      int r=i>>5,k=i&31;
      As[r][k]=b2f(cat[(b*512+t0+r)*576+k0+k]);
    }
    for(int i=tid;i<64*32;i+=256){
      int v=i>>5,k=i&31;
      Bs[k][v]=Wc[(v0+v)*576+k0+k];
    }
    __syncthreads();
    #pragma unroll 8
    for(int kk=0;kk<32;kk++){
      float av[4],bv[4];
      #pragma unroll
      for(int x=0;x<4;x++) av[x]=As[ti*4+x][kk];
      #pragma unroll
      for(int y=0;y<4;y++) bv[y]=Bs[kk][vi*4+y];
      #pragma unroll
      for(int x=0;x<4;x++)
        #pragma unroll
        for(int y=0;y<4;y++) acc[x][y]+=av[x]*bv[y];
    }
    __syncthreads();
  }
  #pragma unroll
  for(int y=0;y<4;y++){
    int v=v0+vi*4+y;
    float bcv=bc[v];
    #pragma unroll
    for(int x=0;x<4;x++){
      int tt=t0+ti*4+x;
      outp[(b*256+v)*512+tt]=acc[x][y]+bcv;
    }
  }
}

extern "C" void kernel_launch(void* const* d_in, const int* in_sizes, int n_in,
                              void* d_out, int out_size, void* d_ws, size_t ws_size,
                              hipStream_t stream) {
  const int*  tokens = (const int*) d_in[0];
  const void* emb    = d_in[1];
  const void* Wi0    = d_in[2];
  const void* Wh0    = d_in[3];
  const void* b0     = d_in[4];
  const void* Wi1    = d_in[5];
  const void* Wh1    = d_in[6];
  const void* b1     = d_in[7];
  const void* W_if   = d_in[8];
  const void* b_if   = d_in[9];
  const void* W_out  = d_in[10];
  const void* b_out  = d_in[11];
  const void* W_fc   = d_in[12];
  const void* b_fc   = d_in[13];

  // sanity: input order must match setup_inputs() dict order
  static const int expect[14] = {64*512, 256*512, 2048*576, 2048*512, 2048,
                                 2048*512, 2048*512, 2048, 135*512, 135,
                                 512*576, 512, 256*512, 256};
  bool ok = (n_in == 14);
  if(ok) for(int i=0;i<14;i++) if(in_sizes[i]!=expect[i]) ok=false;

  // workspace layout (~41.2 MB total)
  int*   flags = (int*)d_ws;                 // 64 ints
  float* embW  = (float*)d_ws + 64;          // 2048*256
  float* h0T   = embW + 2048*256;            // 2*512*64
  float* h1T   = h0T  + 2*512*64;            // 512*64
  float* lrT   = h1T  + 512*64;              // 64*64
  float* Wc    = lrT  + 64*64;               // 256*576
  float* bc    = Wc   + 256*576;             // 256
  float* b_ifF = bc   + 256;                 // 160
  float* W_ifT = b_ifF + 160;                // 512*136 (f32)
  bf16*  cat   = (bf16*)(W_ifT + 512*136);   // 64*512*576

  size_t need = (size_t)(64+2048*256+2*512*64+512*64+64*64+256*576+256+160+512*136)*4
              + (size_t)64*512*576*2;
  if(!ok || ws_size < need){
    hipMemsetAsync(d_out, 0, (size_t)out_size*4, stream);   // signature: clean-zero output (f32)
    return;
  }

  k_detect<<<dim3(1), dim3(256), 0, stream>>>(emb, flags);
  k_embW<<<dim3(2048), dim3(256), 0, stream>>>(emb, Wi0, flags, embW);
  k_wifT<<<dim3((135*512+255)/256), dim3(256), 0, stream>>>(W_if, b_if, flags, W_ifT, b_ifF);
  k_wc  <<<dim3(576),  dim3(256), 0, stream>>>(W_fc, W_out, b_out, b_fc, flags, Wc, bc);

  void* kargs[] = {
    (void*)&tokens, (void*)&Wi0, (void*)&Wh0, (void*)&b0,
    (void*)&Wi1, (void*)&Wh1, (void*)&b1, (void*)&flags,
    (void*)&embW, (void*)&W_ifT, (void*)&b_ifF,
    (void*)&h0T, (void*)&h1T, (void*)&lrT, (void*)&cat
  };
  hipLaunchCooperativeKernel((const void*)k_dnc, dim3(NWG), dim3(TB), kargs, 0, stream);

  k_out<<<dim3(8,4,64), dim3(256), 0, stream>>>(cat, Wc, bc, (float*)d_out);
}

// Round 5
// 65789.685 us; speedup vs baseline: 2.8660x; 2.8660x over previous
//
#include <hip/hip_runtime.h>
#include <hip/hip_bf16.h>

typedef __hip_bfloat16 bf16;

#if __has_builtin(__builtin_amdgcn_fdot2)
#define USE_FDOT2 1
typedef _Float16 h2v __attribute__((ext_vector_type(2)));
#endif

__device__ __forceinline__ float b2f(bf16 x){ return __bfloat162float(x); }
__device__ __forceinline__ float sigf(float x){ return 1.f/(1.f+expf(-x)); }
__device__ __forceinline__ float splus(float x){ return fmaxf(x,0.f)+log1pf(expf(-fabsf(x))); }

// dual-dtype loader: inputs may be float32 or bfloat16; flag chosen at runtime.
__device__ __forceinline__ float ldf(const void* p, int i, int isf32){
  return isf32 ? ((const float*)p)[i] : __bfloat162float(((const bf16*)p)[i]);
}

// pack two floats into one u32 of f16 (or bf16 fallback) for dot2 streaming
__device__ __forceinline__ unsigned pack_pair(float a, float b){
#ifdef USE_FDOT2
  union{ _Float16 f; unsigned short s; } ua, ub;
  ua.f=(_Float16)a; ub.f=(_Float16)b;
  return (unsigned)ua.s | ((unsigned)ub.s<<16);
#else
  union{float f; unsigned u;} za, zb; za.f=a; zb.f=b;
  unsigned x=za.u, y=zb.u;
  unsigned ra=(x + 0x7fffu + ((x>>16)&1u))>>16;
  unsigned rb=(y + 0x7fffu + ((y>>16)&1u))>>16;
  return ra | (rb<<16);
#endif
}

__device__ __forceinline__ float dot2(unsigned w, unsigned x, float acc){
#ifdef USE_FDOT2
  union{ unsigned u; h2v h; } uw, ux; uw.u=w; ux.u=x;
  return __builtin_amdgcn_fdot2(uw.h, ux.h, acc, false);
#else
  union{float f; unsigned u;} w0,w1,x0,x1;
  w0.u = w<<16; w1.u = w & 0xffff0000u; x0.u = x<<16; x1.u = x & 0xffff0000u;
  return acc + w0.f*x0.f + w1.f*x1.f;
#endif
}

// ---------------- dtype detection: read emb as bf16; f32 data shows huge exponents ----------------
__global__ void k_detect(const void* __restrict__ emb, int* __restrict__ flag){
  __shared__ float mx[256];
  int tid=threadIdx.x;
  float v = fabsf(__bfloat162float(((const bf16*)emb)[tid]));
  mx[tid]=v; __syncthreads();
  for(int s=128;s>0;s>>=1){ if(tid<s) mx[tid]=fmaxf(mx[tid],mx[tid+s]); __syncthreads(); }
  if(tid==0) flag[0] = (mx[0]>1000.f) ? 1 : 0;
}

// ---------------- setup kernels ----------------

// embWT[v][r] = b0[r] + sum_k emb[v][k]*Wi0[r][k]   (v<256, r<2048, k<512), transposed for coalesced row reads
__global__ void k_embW(const void* __restrict__ emb, const void* __restrict__ Wi0,
                       const void* __restrict__ b0,
                       const int* __restrict__ flags, float* __restrict__ embWT){
  int f=flags[0];
  int row = blockIdx.x;              // 0..2047
  __shared__ float w[512];
  for(int k=threadIdx.x;k<512;k+=256) w[k]=ldf(Wi0,row*576+k,f);
  __syncthreads();
  int v = threadIdx.x;               // 0..255
  float acc=ldf(b0,row,f);
  #pragma unroll 4
  for(int k=0;k<512;k++) acc += ldf(emb,v*512+k,f)*w[k];
  embWT[v*2048+row]=acc;
}

// WA8: phase-A weights, packed pairs, layout [k8][2048 rows][4 u32], K=576: A[r][k] = k<512 ? Wh0[r][k] : Wi0[r][k]
__global__ void k_wa8(const void* __restrict__ Wh0, const void* __restrict__ Wi0,
                      const int* __restrict__ flags, unsigned* __restrict__ WA8u){
  int f=flags[0];
  int idx=blockIdx.x*256+threadIdx.x;         // < 72*2048*4 = 589824
  if(idx>=589824) return;
  int j = idx & 3; int r = (idx>>2) & 2047; int k8 = idx >> 13;
  int k = k8*8 + j*2;
  float v0 = (k  <512) ? ldf(Wh0, r*512+k,   f) : ldf(Wi0, r*576+k,   f);
  float v1 = (k+1<512) ? ldf(Wh0, r*512+k+1, f) : ldf(Wi0, r*576+k+1, f);
  WA8u[idx]=pack_pair(v0,v1);
}

// WB8: phase-B weights, layout [k8][2048][4], K=1024: B[r][k] = k<512 ? Wi1[r][k] : Wh1[r][k-512]
__global__ void k_wb8(const void* __restrict__ Wi1, const void* __restrict__ Wh1,
                      const int* __restrict__ flags, unsigned* __restrict__ WB8u){
  int f=flags[0];
  int idx=blockIdx.x*256+threadIdx.x;         // < 128*2048*4 = 1048576
  if(idx>=1048576) return;
  int j = idx & 3; int r = (idx>>2) & 2047; int k8 = idx >> 13;
  int k = k8*8 + j*2;
  float v0 = (k  <512) ? ldf(Wi1, r*512+k,   f) : ldf(Wh1, r*512+k-512,   f);
  float v1 = (k+1<512) ? ldf(Wi1, r*512+k+1, f) : ldf(Wh1, r*512+k+1-512, f);
  WB8u[idx]=pack_pair(v0,v1);
}

// W_ifT[k][v] (pad 136, f32) transpose of W_if (135x512); b_if -> f32
__global__ void k_wifT(const void* __restrict__ W_if, const void* __restrict__ b_if,
                       const int* __restrict__ flags,
                       float* __restrict__ W_ifT, float* __restrict__ b_ifF){
  int f=flags[0];
  int idx=blockIdx.x*256+threadIdx.x;
  if(idx<135*512){ int v=idx/512, k=idx-v*512; W_ifT[k*136+v]=ldf(W_if,idx,f); }
  if(idx<135) b_ifF[idx]=ldf(b_if,idx,f);
}

// Wc[v][j] = sum_d W_fc[v][d]*W_out[d][j];  bc[v] = b_fc[v] + W_fc[v,:]@b_out
__global__ void k_wc(const void* __restrict__ W_fc, const void* __restrict__ W_out,
                     const void* __restrict__ b_out, const void* __restrict__ b_fc,
                     const int* __restrict__ flags,
                     float* __restrict__ Wc, float* __restrict__ bc){
  int f=flags[0];
  int idx=blockIdx.x*256+threadIdx.x;    // 576 blocks * 256 = 147456
  int v=idx/576, j=idx-v*576;
  float acc=0.f;
  #pragma unroll 4
  for(int d=0;d<512;d++) acc += ldf(W_fc,v*512+d,f)*ldf(W_out,d*576+j,f);
  Wc[idx]=acc;
  if(j==0){
    float a=ldf(b_fc,v,f);
    for(int d=0;d<512;d++) a += ldf(W_fc,v*512+d,f)*ldf(b_out,d,f);
    bc[v]=a;
  }
}

// ---------------- batch-parallel recurrence: 64 wgs x 1024 threads, NO grid sync ----------------
// wg = one batch element. All state in LDS. Weights streamed (f16 pairs) from L2/IC via dot2.
__global__ void __launch_bounds__(1024) k_dnc2(
    const int* __restrict__ tokens,
    const void* __restrict__ b1, const int* __restrict__ flags,
    const float* __restrict__ embWT,
    const unsigned* __restrict__ WA8u, const unsigned* __restrict__ WB8u,
    const float* __restrict__ W_ifT, const float* __restrict__ b_ifF,
    bf16* __restrict__ cat)
{
  __shared__ float pre[2048];
  __shared__ float b1L[2048];
  __shared__ float h0[512], h1[512], c0[512], c1[512], oc[512];
  __shared__ float lr64[64];
  __shared__ int   toks[512];
  __shared__ __align__(16) unsigned hA8u[288];
  __shared__ __align__(16) unsigned hB8u[512];
  __shared__ float xis[136];
  __shared__ float xpart[3*136];
  __shared__ float s_mem[80], s_mem2[80];
  __shared__ float s_link[25], s_link2[25];
  __shared__ float s_prec[5], s_prec2[5];
  __shared__ float s_rwp[20], s_rw[20];
  __shared__ float s_wwp[5], s_ww[5], s_usage[5];
  __shared__ float s_wl[5];
  __shared__ float s_rl[20], s_fwd[20], s_bwd[20];
  __shared__ float s_wsum;

  const int b   = blockIdx.x;
  const int tid = threadIdx.x;
  const int f32i = flags[0];

  // init
  b1L[tid]      = ldf(b1, tid,      f32i);
  b1L[1024+tid] = ldf(b1, 1024+tid, f32i);
  if(tid<512){ h0[tid]=0.f; h1[tid]=0.f; c0[tid]=0.f; c1[tid]=0.f; oc[tid]=0.f;
               toks[tid]=tokens[b*512+tid]; }
  if(tid<64)  lr64[tid]=0.f;
  if(tid<80)  s_mem[tid]=0.f;
  if(tid>=128&&tid<153) s_link[tid-128]=0.f;
  if(tid>=160&&tid<165) s_prec[tid-160]=0.f;
  if(tid>=192&&tid<212) s_rwp[tid-192]=0.f;
  if(tid>=224&&tid<229) s_wwp[tid-224]=0.f;
  if(tid>=256&&tid<261) s_usage[tid-256]=0.f;
  __syncthreads();

  const uint4* WA8v = (const uint4*)WA8u;
  const uint4* WB8v = (const uint4*)WB8u;
  const uint4* hA8v = (const uint4*)hA8u;
  const uint4* hB8v = (const uint4*)hB8u;

  for(int t=0;t<512;t++){
    // S1: pack [h0 ; lr] -> f16 pairs
    if(tid<288){
      int p=2*tid;
      float v0 = (p  <512)? h0[p]   : lr64[p-512];
      float v1 = (p+1<512)? h0[p+1] : lr64[p+1-512];
      hA8u[tid]=pack_pair(v0,v1);
    }
    __syncthreads();
    // S2: phase A — g0 rows tid and 1024+tid; acc init = embWT[tok][r] (b0 folded)
    {
      int tok = toks[t];
      float a0=embWT[tok*2048+tid], a1=embWT[tok*2048+1024+tid];
      #pragma unroll 4
      for(int k8=0;k8<72;k8++){
        uint4 w0 = WA8v[(k8<<11)+tid];
        uint4 w1 = WA8v[(k8<<11)+1024+tid];
        uint4 hh = hA8v[k8];
        a0=dot2(w0.x,hh.x,a0); a0=dot2(w0.y,hh.y,a0); a0=dot2(w0.z,hh.z,a0); a0=dot2(w0.w,hh.w,a0);
        a1=dot2(w1.x,hh.x,a1); a1=dot2(w1.y,hh.y,a1); a1=dot2(w1.z,hh.z,a1); a1=dot2(w1.w,hh.w,a1);
      }
      pre[tid]=a0; pre[1024+tid]=a1;
    }
    __syncthreads();
    // S3: LSTM0 cell
    if(tid<512){
      float gi=pre[tid], gf=pre[512+tid], gg=pre[1024+tid], go=pre[1536+tid];
      float c=sigf(gf)*c0[tid]+sigf(gi)*tanhf(gg);
      c0[tid]=c; h0[tid]=sigf(go)*tanhf(c);
    }
    __syncthreads();
    // S4: pack [h0' ; h1_old]
    if(tid<512){
      int p=2*tid;
      float v0 = (p  <512)? h0[p]   : h1[p-512];
      float v1 = (p+1<512)? h0[p+1] : h1[p+1-512];
      hB8u[tid]=pack_pair(v0,v1);
    }
    __syncthreads();
    // S5: phase B — g1 rows
    {
      float a0=b1L[tid], a1=b1L[1024+tid];
      #pragma unroll 4
      for(int k8=0;k8<128;k8++){
        uint4 w0 = WB8v[(k8<<11)+tid];
        uint4 w1 = WB8v[(k8<<11)+1024+tid];
        uint4 hh = hB8v[k8];
        a0=dot2(w0.x,hh.x,a0); a0=dot2(w0.y,hh.y,a0); a0=dot2(w0.z,hh.z,a0); a0=dot2(w0.w,hh.w,a0);
        a1=dot2(w1.x,hh.x,a1); a1=dot2(w1.y,hh.y,a1); a1=dot2(w1.z,hh.z,a1); a1=dot2(w1.w,hh.w,a1);
      }
      pre[tid]=a0; pre[1024+tid]=a1;
    }
    __syncthreads();
    // S6: LSTM1 cell + out=clip + cat store
    if(tid<512){
      float gi=pre[tid], gf=pre[512+tid], gg=pre[1024+tid], go=pre[1536+tid];
      float c=sigf(gf)*c1[tid]+sigf(gi)*tanhf(gg);
      c1[tid]=c;
      float h=sigf(go)*tanhf(c);
      h1[tid]=h;
      float out=fminf(fmaxf(h,-20.f),20.f);
      oc[tid]=out;
      cat[(b*512+t)*576+tid]=__float2bfloat16(out);
    }
    __syncthreads();
    // S7: interface vector xi = b_if + W_if @ oc  (3-way K split)
    if(tid<405){
      int q=tid/135, v=tid-q*135;
      int k0=q*171, k1=k0+171; if(k1>512)k1=512;
      float a=0.f;
      for(int k=k0;k<k1;k++) a += oc[k]*W_ifT[k*136+v];
      xpart[q*136+v]=a;
    }
    __syncthreads();
    if(tid<135) xis[tid]=b_ifF[tid]+xpart[tid]+xpart[136+tid]+xpart[272+tid];
    __syncthreads();
    // M1: usage retention + write-content logits
    if(tid<5){
      int m=tid;
      float u=s_usage[m]+(1.f-s_usage[m])*s_wwp[m];
      float psi=1.f;
      #pragma unroll
      for(int r=0;r<4;r++) psi *= 1.f - sigf(xis[117+r])*s_rwp[r*5+m];
      u*=psi;
      s_usage[m]=u;
      float nm=0.f,dt=0.f,nk=0.f;
      #pragma unroll
      for(int w=0;w<16;w++){
        float mv=s_mem[m*16+w], kv=tanhf(xis[68+w]);
        nm+=mv*mv; dt+=mv*kv; nk+=kv*kv;
      }
      float sim=dt/((sqrtf(nm)+1e-6f)*(sqrtf(nk)+1e-6f));
      s_wl[m]=sim*splus(xis[84]);
    }
    __syncthreads();
    // M2: wcw softmax + allocation + ww (serial, tiny)
    if(tid==0){
      float mx=-1e30f;
      for(int m=0;m<5;m++) mx=fmaxf(mx,s_wl[m]);
      float e[5]; float s=0.f;
      for(int m=0;m<5;m++){ e[m]=expf(s_wl[m]-mx); s+=e[m]; }
      float u[5]; int id[5];
      for(int m=0;m<5;m++){ u[m]=1e-6f+(1.f-1e-6f)*s_usage[m]; id[m]=m; }
      for(int i=1;i<5;i++){
        float uv=u[i]; int iv=id[i]; int j=i-1;
        while(j>=0&&u[j]>uv){u[j+1]=u[j];id[j+1]=id[j];j--;}
        u[j+1]=uv; id[j+1]=iv;
      }
      float alm[5]; float prod=1.f;
      for(int i=0;i<5;i++){ alm[id[i]]=(1.f-u[i])*prod; prod*=u[i]; }
      float ag=sigf(xis[121]), wgg=sigf(xis[122]);
      float wsum=0.f;
      for(int m=0;m<5;m++){
        float wcw=e[m]/s;
        float w_=wgg*(ag*alm[m]+(1.f-ag)*wcw);
        s_ww[m]=w_; wsum+=w_;
      }
      s_wsum=wsum;
    }
    __syncthreads();
    // M3: mem2, link2 (eye-masked), prec2
    if(tid<80){
      int m=tid>>4,w=tid&15;
      float er=sigf(xis[85+w]), wv=tanhf(xis[101+w]);
      float w_=s_ww[m];
      s_mem2[tid]=s_mem[tid]*(1.f-w_*er)+w_*wv;
    } else if(tid>=128&&tid<153){
      int q=tid-128; int i=q/5, j=q-5*i;
      s_link2[q]=(i==j)?0.f:((1.f-s_ww[i]-s_ww[j])*s_link[q]+s_ww[i]*s_prec[j]);
    } else if(tid>=160&&tid<165){
      int j=tid-160;
      s_prec2[j]=(1.f-s_wsum)*s_prec[j]+s_ww[j];
    }
    __syncthreads();
    // M4: read-content logits, fwd, bwd
    if(tid<20){
      int r=tid/5,m=tid-5*(tid/5);
      float nm=0.f,dt=0.f,nk=0.f;
      #pragma unroll
      for(int w=0;w<16;w++){
        float mv=s_mem2[m*16+w], kv=tanhf(xis[r*16+w]);
        nm+=mv*mv; dt+=mv*kv; nk+=kv*kv;
      }
      float sim=dt/((sqrtf(nm)+1e-6f)*(sqrtf(nk)+1e-6f));
      s_rl[tid]=sim*splus(xis[64+r]);
    } else if(tid>=64&&tid<84){
      int q=tid-64; int r=q/5, i=q-5*r;
      float a=0.f;
      #pragma unroll
      for(int j=0;j<5;j++) a+=s_link2[i*5+j]*s_rwp[r*5+j];
      s_fwd[r*5+i]=a;
    } else if(tid>=96&&tid<116){
      int q=tid-96; int r=q/5, j=q-5*r;
      float a=0.f;
      #pragma unroll
      for(int i=0;i<5;i++) a+=s_link2[i*5+j]*s_rwp[r*5+i];
      s_bwd[r*5+j]=a;
    }
    __syncthreads();
    // M5: rcw softmax + mode mix
    if(tid<20){
      int r=tid/5;
      float mx=-1e30f;
      for(int m=0;m<5;m++) mx=fmaxf(mx,s_rl[r*5+m]);
      float s=0.f;
      for(int m=0;m<5;m++) s+=expf(s_rl[r*5+m]-mx);
      float rcw=expf(s_rl[tid]-mx)/s;
      float q0=xis[123+3*r],q1=xis[124+3*r],q2=xis[125+3*r];
      float m3=fmaxf(q0,fmaxf(q1,q2));
      float e0=expf(q0-m3),e1=expf(q1-m3),e2=expf(q2-m3);
      float inv=1.f/(e0+e1+e2);
      s_rw[tid]=(e0*s_bwd[tid]+e1*s_fwd[tid]+e2*rcw)*inv;
    }
    __syncthreads();
    // M6: read vectors; commit carries
    if(tid<64){
      int r=tid>>4,w=tid&15;
      float a=0.f;
      #pragma unroll
      for(int m=0;m<5;m++) a+=s_rw[r*5+m]*s_mem2[m*16+w];
      lr64[tid]=a;
      cat[(b*512+t)*576+512+tid]=__float2bfloat16(a);
    } else if(tid>=128&&tid<208){ s_mem [tid-128]=s_mem2 [tid-128];
    } else if(tid>=208&&tid<233){ s_link[tid-208]=s_link2[tid-208];
    } else if(tid>=240&&tid<245){ s_prec[tid-240]=s_prec2[tid-240];
    } else if(tid>=256&&tid<276){ s_rwp [tid-256]=s_rw   [tid-256];
    } else if(tid>=288&&tid<293){ s_wwp [tid-288]=s_ww   [tid-288]; }
    __syncthreads();
  }
}

// ---------------- final output GEMM: logits[b][v][t] = bc[v] + cat[b,t,:] . Wc[v,:] ----------------
__global__ void __launch_bounds__(256) k_out(const bf16* __restrict__ cat,
                                             const float* __restrict__ Wc,
                                             const float* __restrict__ bc,
                                             float* __restrict__ outp){
  int t0=blockIdx.x*64, v0=blockIdx.y*64, b=blockIdx.z;
  __shared__ float As[64][33];
  __shared__ float Bs[32][65];
  int tid=threadIdx.x;
  int ti=tid>>4, vi=tid&15;
  float acc[4][4]={};
  for(int k0=0;k0<576;k0+=32){
    for(int i=tid;i<64*32;i+=256){
      int r=i>>5,k=i&31;
      As[r][k]=b2f(cat[(b*512+t0+r)*576+k0+k]);
    }
    for(int i=tid;i<64*32;i+=256){
      int v=i>>5,k=i&31;
      Bs[k][v]=Wc[(v0+v)*576+k0+k];
    }
    __syncthreads();
    #pragma unroll 8
    for(int kk=0;kk<32;kk++){
      float av[4],bv[4];
      #pragma unroll
      for(int x=0;x<4;x++) av[x]=As[ti*4+x][kk];
      #pragma unroll
      for(int y=0;y<4;y++) bv[y]=Bs[kk][vi*4+y];
      #pragma unroll
      for(int x=0;x<4;x++)
        #pragma unroll
        for(int y=0;y<4;y++) acc[x][y]+=av[x]*bv[y];
    }
    __syncthreads();
  }
  #pragma unroll
  for(int y=0;y<4;y++){
    int v=v0+vi*4+y;
    float bcv=bc[v];
    #pragma unroll
    for(int x=0;x<4;x++){
      int tt=t0+ti*4+x;
      outp[(b*256+v)*512+tt]=acc[x][y]+bcv;
    }
  }
}

extern "C" void kernel_launch(void* const* d_in, const int* in_sizes, int n_in,
                              void* d_out, int out_size, void* d_ws, size_t ws_size,
                              hipStream_t stream) {
  const int*  tokens = (const int*) d_in[0];
  const void* emb    = d_in[1];
  const void* Wi0    = d_in[2];
  const void* Wh0    = d_in[3];
  const void* b0     = d_in[4];
  const void* Wi1    = d_in[5];
  const void* Wh1    = d_in[6];
  const void* b1     = d_in[7];
  const void* W_if   = d_in[8];
  const void* b_if   = d_in[9];
  const void* W_out  = d_in[10];
  const void* b_out  = d_in[11];
  const void* W_fc   = d_in[12];
  const void* b_fc   = d_in[13];

  // sanity: input order must match setup_inputs() dict order
  static const int expect[14] = {64*512, 256*512, 2048*576, 2048*512, 2048,
                                 2048*512, 2048*512, 2048, 135*512, 135,
                                 512*576, 512, 256*512, 256};
  bool ok = (n_in == 14);
  if(ok) for(int i=0;i<14;i++) if(in_sizes[i]!=expect[i]) ok=false;

  // workspace layout (~47.2 MB total)
  int*      flags = (int*)d_ws;                   // 64 ints
  float*    embWT = (float*)d_ws + 64;            // 256*2048 f32        (2 MB)
  unsigned* WA8u  = (unsigned*)(embWT + 256*2048);// 72*2048*4 u32       (2.36 MB)
  unsigned* WB8u  = WA8u + 589824;                // 128*2048*4 u32      (4.19 MB)
  float*    W_ifT = (float*)(WB8u + 1048576);     // 512*136 f32         (0.28 MB)
  float*    b_ifF = W_ifT + 512*136;              // 160
  float*    Wc    = b_ifF + 160;                  // 256*576 f32         (0.59 MB)
  float*    bc    = Wc + 256*576;                 // 256
  bf16*     cat   = (bf16*)(bc + 256);            // 64*512*576 bf16     (37.75 MB)

  size_t need = (size_t)(64 + 256*2048)*4 + (size_t)(589824+1048576)*4
              + (size_t)(512*136 + 160 + 256*576 + 256)*4
              + (size_t)64*512*576*2;
  if(!ok || ws_size < need){
    hipMemsetAsync(d_out, 0, (size_t)out_size*4, stream);   // signature: clean-zero output (f32)
    return;
  }

  k_detect<<<dim3(1), dim3(256), 0, stream>>>(emb, flags);
  k_embW<<<dim3(2048), dim3(256), 0, stream>>>(emb, Wi0, b0, flags, embWT);
  k_wa8 <<<dim3((589824+255)/256),  dim3(256), 0, stream>>>(Wh0, Wi0, flags, WA8u);
  k_wb8 <<<dim3((1048576+255)/256), dim3(256), 0, stream>>>(Wi1, Wh1, flags, WB8u);
  k_wifT<<<dim3((135*512+255)/256), dim3(256), 0, stream>>>(W_if, b_if, flags, W_ifT, b_ifF);
  k_wc  <<<dim3(576),  dim3(256), 0, stream>>>(W_fc, W_out, b_out, b_fc, flags, Wc, bc);

  k_dnc2<<<dim3(64), dim3(1024), 0, stream>>>(tokens, b1, flags, embWT,
                                              WA8u, WB8u, W_ifT, b_ifF, cat);

  k_out<<<dim3(8,4,64), dim3(256), 0, stream>>>(cat, Wc, bc, (float*)d_out);
}

// Round 6
// 34345.782 us; speedup vs baseline: 5.4899x; 1.9155x over previous
//
#include <hip/hip_runtime.h>
#include <hip/hip_bf16.h>

typedef __hip_bfloat16 bf16;
typedef _Float16 f16;
typedef _Float16 f16x8 __attribute__((ext_vector_type(8)));
typedef float f32x4 __attribute__((ext_vector_type(4)));
typedef unsigned long long u64;
typedef unsigned short ushort_t;

__device__ __forceinline__ float b2f(bf16 x){ return __bfloat162float(x); }
__device__ __forceinline__ float sigf(float x){ return 1.f/(1.f+expf(-x)); }
__device__ __forceinline__ float splus(float x){ return fmaxf(x,0.f)+log1pf(expf(-fabsf(x))); }
__device__ __forceinline__ float ldf(const void* p, int i, int isf32){
  return isf32 ? ((const float*)p)[i] : __bfloat162float(((const bf16*)p)[i]);
}
// agent-scope coherent ops (cross-XCD visibility without L2 flush storms)
__device__ __forceinline__ void ast64(u64* p, u64 v){ __hip_atomic_store(p, v, __ATOMIC_RELAXED, __HIP_MEMORY_SCOPE_AGENT); }
__device__ __forceinline__ u64 ald64(u64* p){ return __hip_atomic_load(p, __ATOMIC_RELAXED, __HIP_MEMORY_SCOPE_AGENT); }
__device__ __forceinline__ void ast32(unsigned* p, unsigned v){ __hip_atomic_store(p, v, __ATOMIC_RELAXED, __HIP_MEMORY_SCOPE_AGENT); }

union U4H8 { uint4 u; f16x8 h; };
union U64H4 { u64 u; f16 h[4]; };
union U32H2 { unsigned u; f16 h[2]; };
union H16 { f16 h; ushort_t s; };

// ---------------- dtype detect + barrier-counter zero ----------------
__global__ void k_detect(const void* __restrict__ emb, int* __restrict__ flag){
  __shared__ float mx[256];
  int tid=threadIdx.x;
  float v = fabsf(__bfloat162float(((const bf16*)emb)[tid]));
  mx[tid]=v; __syncthreads();
  for(int s=128;s>0;s>>=1){ if(tid<s) mx[tid]=fmaxf(mx[tid],mx[tid+s]); __syncthreads(); }
  if(tid==0){ flag[0] = (mx[0]>1000.f) ? 1 : 0; flag[1] = 0; }  // flag[1] = barrier ctr
}

// ---------------- setup ----------------
// embW[row][v] = b0[row] + sum_k emb[v][k]*Wi0[row][k]
__global__ void k_embW(const void* __restrict__ emb, const void* __restrict__ Wi0,
                       const void* __restrict__ b0,
                       const int* __restrict__ flags, float* __restrict__ embW){
  int f=flags[0];
  int row = blockIdx.x;
  __shared__ float w[512];
  for(int k=threadIdx.x;k<512;k+=256) w[k]=ldf(Wi0,row*576+k,f);
  __syncthreads();
  int v = threadIdx.x;
  float acc=ldf(b0,row,f);
  #pragma unroll 4
  for(int k=0;k<512;k++) acc += ldf(emb,v*512+k,f)*w[k];
  embW[row*256+v]=acc;
}

// prepack phase-A weights into MFMA A-fragment order (f16)
// addr = ((q*8+v)*5 + c)*512 + l*8 + j ; chunk=c*4+(v>>1); K=[h0(512:Wh0), lr(64:Wi0[:,512:])]
__global__ void k_wpkA(const void* __restrict__ Wh0, const void* __restrict__ Wi0,
                       const int* __restrict__ flags, ushort_t* __restrict__ PA){
  int f=flags[0];
  int idx=blockIdx.x*256+threadIdx.x;
  if(idx>=1310720) return;
  int j=idx&7, lcl=(idx>>3)&63, fi=idx>>9;
  int c=fi%5, tq=fi/5, v=tq&7, q=tq>>3;
  int kh=v>>1, rt=v&1, m=lcl&15, quad=lcl>>4;
  int chunk=c*4+kh;
  int ri=rt*16+m, g=ri>>3, u=ri&7, row=(g<<9)+(q<<3)+u;
  int k=chunk*32+quad*8+j;
  float val=0.f;
  if(chunk<18) val = (k<512)? ldf(Wh0,row*512+k,f) : ldf(Wi0,row*576+k,f);
  H16 hh; hh.h=(f16)val; PA[idx]=hh.s;
}
// phase-B: addr = ((q*8+v)*8 + c)*512 + l*8 + j ; K=[h0'(512:Wi1), h1old(512:Wh1)]
__global__ void k_wpkB(const void* __restrict__ Wi1, const void* __restrict__ Wh1,
                       const int* __restrict__ flags, ushort_t* __restrict__ PB){
  int f=flags[0];
  int idx=blockIdx.x*256+threadIdx.x;
  if(idx>=2097152) return;
  int j=idx&7, lcl=(idx>>3)&63, c=(idx>>9)&7, v=(idx>>12)&7, q=idx>>15;
  int kh=v>>1, rt=v&1, m=lcl&15, quad=lcl>>4;
  int chunk=c*4+kh;
  int ri=rt*16+m, g=ri>>3, u=ri&7, row=(g<<9)+(q<<3)+u;
  int k=chunk*32+quad*8+j;
  float val = (k<512)? ldf(Wi1,row*512+k,f) : ldf(Wh1,row*512+k-512,f);
  H16 hh; hh.h=(f16)val; PB[idx]=hh.s;
}

__global__ void k_wifT(const void* __restrict__ W_if, const void* __restrict__ b_if,
                       const int* __restrict__ flags,
                       float* __restrict__ W_ifT, float* __restrict__ b_ifF){
  int f=flags[0];
  int idx=blockIdx.x*256+threadIdx.x;
  if(idx<135*512){ int v=idx/512, k=idx-v*512; W_ifT[k*136+v]=ldf(W_if,idx,f); }
  if(idx<135) b_ifF[idx]=ldf(b_if,idx,f);
}

__global__ void k_wc(const void* __restrict__ W_fc, const void* __restrict__ W_out,
                     const void* __restrict__ b_out, const void* __restrict__ b_fc,
                     const int* __restrict__ flags,
                     float* __restrict__ Wc, float* __restrict__ bc){
  int f=flags[0];
  int idx=blockIdx.x*256+threadIdx.x;
  int v=idx/576, j=idx-v*576;
  float acc=0.f;
  #pragma unroll 4
  for(int d=0;d<512;d++) acc += ldf(W_fc,v*512+d,f)*ldf(W_out,d*576+j,f);
  Wc[idx]=acc;
  if(j==0){
    float a=ldf(b_fc,v,f);
    for(int d=0;d<512;d++) a += ldf(W_fc,v*512+d,f)*ldf(b_out,d,f);
    bc[v]=a;
  }
}

// ---------------- cooperative recurrence: 64 wgs x 512 thr, row-partitioned, MFMA ----------------
__global__ void __launch_bounds__(512) k_dnc3(
    const int* __restrict__ tokens, const void* __restrict__ b1, const int* __restrict__ flags,
    const float* __restrict__ embW, const ushort_t* __restrict__ PA, const ushort_t* __restrict__ PB,
    const float* __restrict__ W_ifT, const float* __restrict__ b_ifF,
    u64* GH0, u64* GH1, u64* GLR, unsigned* ctr,
    bf16* __restrict__ cat)
{
  const int q   = blockIdx.x;
  const int tid = threadIdx.x;
  const int wv  = tid>>6, l = tid&63;
  const int lm  = l&15,  quad = l>>4;
  const int rt  = wv&1,  kh = wv>>1;
  const int f32i = flags[0];

  __shared__ u64  HBuf[2][2048];       // 2 x (16 k8-groups x 64 batch x 16B)
  __shared__ float preact[32*65];      // padded 65 to break bank conflicts on ds_add
  __shared__ float oc[512];
  __shared__ float b1L[32];
  __shared__ float xis[136], xpart[3*136];
  __shared__ float s_mem[80], s_mem2[80], s_link[25], s_link2[25];
  __shared__ float s_prec[5], s_prec2[5], s_rwp[20], s_rw[20];
  __shared__ float s_wwp[5], s_ww[5], s_usage[5], s_wl[5];
  __shared__ float s_rl[20], s_fwd[20], s_bwd[20], s_wsum;
  __shared__ float rvbuf[64];

  // resident weight fragments
  f16x8 fa[5], fb[8];
  {
    const uint4* PAv=(const uint4*)PA;
    const uint4* PBv=(const uint4*)PB;
    #pragma unroll
    for(int c=0;c<5;c++){ U4H8 t4; t4.u = PAv[((q*8+wv)*5+c)*64 + l]; fa[c]=t4.h; }
    #pragma unroll
    for(int c=0;c<8;c++){ U4H8 t4; t4.u = PBv[((q*8+wv)*8+c)*64 + l]; fb[c]=t4.h; }
  }
  if(tid<32){ int g=tid>>3,u=tid&7; b1L[tid]=ldf(b1,(g<<9)+(q<<3)+u,f32i); }
  // DNC per-batch state
  if(tid<80) s_mem[tid]=0.f;
  if(tid>=128&&tid<153) s_link[tid-128]=0.f;
  if(tid>=160&&tid<165) s_prec[tid-160]=0.f;
  if(tid>=192&&tid<212) s_rwp[tid-192]=0.f;
  if(tid>=224&&tid<229) s_wwp[tid-224]=0.f;
  if(tid>=256&&tid<261) s_usage[tid-256]=0.f;
  // zero parity-1 handoff buffers (read at t=0)
  if(tid<128){ ast64(&GH0[8192 + (q*64+(tid>>1))*2 + (tid&1)], 0ull);
               ast64(&GH1[8192 + (q*64+(tid>>1))*2 + (tid&1)], 0ull); }
  if(tid<16){  ast64(&GLR[1024 + ((tid>>1)*64+q)*2 + (tid&1)], 0ull); }
  float c0s[8], c1s[8];
  #pragma unroll
  for(int u=0;u<8;u++){ c0s[u]=0.f; c1s[u]=0.f; }

  unsigned nb=0;
#define GBAR() do{ nb++; __syncthreads(); \
  if(tid==0){ __hip_atomic_fetch_add(ctr,1u,__ATOMIC_ACQ_REL,__HIP_MEMORY_SCOPE_AGENT); \
    while(__hip_atomic_load(ctr,__ATOMIC_ACQUIRE,__HIP_MEMORY_SCOPE_AGENT) < nb*64u) __builtin_amdgcn_s_sleep(2); } \
  __syncthreads(); }while(0)

  GBAR();   // init visible

  for(int t=0;t<512;t++){
    const int p=t&1, pm=p^1;
    // ---- phase A: issue fills (h0(t-1) + lr(t-1)) into regs ----
    u64 ra[18];
    #pragma unroll
    for(int i=0;i<16;i++) ra[i]=ald64(&GH0[pm*8192 + tid + 512*i]);
    #pragma unroll
    for(int i=16;i<18;i++) ra[i]=ald64(&GLR[pm*1024 + tid + 512*(i-16)]);
    float em[4][8];
    if(wv==0){
      int tokb = tokens[l*512+t];
      #pragma unroll
      for(int g=0;g<4;g++)
        #pragma unroll
        for(int u=0;u<8;u++)
          em[g][u]=embW[((g<<9)+(q<<3)+u)*256 + tokb];
    }
    for(int i=tid;i<2080;i+=512) preact[i]=0.f;
    f32x4 acc[4];
    #pragma unroll
    for(int bt=0;bt<4;bt++) acc[bt]=(f32x4){0.f,0.f,0.f,0.f};
    #pragma unroll
    for(int blk=0;blk<5;blk++){
      int nreg=(blk<4)?4:2;
      #pragma unroll
      for(int jj=0;jj<4;jj++) if(jj<nreg) HBuf[blk&1][tid+512*jj]=ra[blk*4+jj];
      __syncthreads();
      if(blk<4 || kh<2){
        const f16x8* hb=(const f16x8*)(&HBuf[blk&1][0]);
        #pragma unroll
        for(int bt=0;bt<4;bt++){
          f16x8 bfr = hb[(kh*4+quad)*64 + bt*16 + lm];
          acc[bt]=__builtin_amdgcn_mfma_f32_16x16x32_f16(fa[blk],bfr,acc[bt],0,0,0);
        }
      }
    }
    #pragma unroll
    for(int bt=0;bt<4;bt++)
      #pragma unroll
      for(int r=0;r<4;r++)
        atomicAdd(&preact[(rt*16+quad*4+r)*65 + bt*16 + lm], acc[bt][r]);
    __syncthreads();
    if(wv==0){   // LSTM0 cell for owned units, publish h0'(t)
      U64H4 pk0, pk1;
      #pragma unroll
      for(int u=0;u<8;u++){
        float gi=preact[(u   )*65+l]+em[0][u];
        float gf=preact[(8+u )*65+l]+em[1][u];
        float gg=preact[(16+u)*65+l]+em[2][u];
        float go=preact[(24+u)*65+l]+em[3][u];
        float c=sigf(gf)*c0s[u]+sigf(gi)*tanhf(gg);
        c0s[u]=c;
        float h=sigf(go)*tanhf(c);
        if(u<4) pk0.h[u]=(f16)h; else pk1.h[u-4]=(f16)h;
      }
      ast64(&GH0[p*8192+(q*64+l)*2  ], pk0.u);
      ast64(&GH0[p*8192+(q*64+l)*2+1], pk1.u);
    }
    GBAR();  // alpha: h0'(t) visible

    // ---- phase B ----
    u64 rb[32];
    #pragma unroll
    for(int i=0;i<16;i++) rb[i]=ald64(&GH0[p*8192 + tid + 512*i]);
    #pragma unroll
    for(int i=16;i<32;i++) rb[i]=ald64(&GH1[pm*8192 + tid + 512*(i-16)]);
    for(int i=tid;i<2080;i+=512) preact[i]=0.f;
    #pragma unroll
    for(int bt=0;bt<4;bt++) acc[bt]=(f32x4){0.f,0.f,0.f,0.f};
    #pragma unroll
    for(int blk=0;blk<8;blk++){
      #pragma unroll
      for(int jj=0;jj<4;jj++) HBuf[blk&1][tid+512*jj]=rb[blk*4+jj];
      __syncthreads();
      const f16x8* hb=(const f16x8*)(&HBuf[blk&1][0]);
      #pragma unroll
      for(int bt=0;bt<4;bt++){
        f16x8 bfr = hb[(kh*4+quad)*64 + bt*16 + lm];
        acc[bt]=__builtin_amdgcn_mfma_f32_16x16x32_f16(fb[blk],bfr,acc[bt],0,0,0);
      }
    }
    #pragma unroll
    for(int bt=0;bt<4;bt++)
      #pragma unroll
      for(int r=0;r<4;r++)
        atomicAdd(&preact[(rt*16+quad*4+r)*65 + bt*16 + lm], acc[bt][r]);
    __syncthreads();
    if(wv==0){   // LSTM1 cell, publish h1(t)
      U64H4 pk0, pk1;
      #pragma unroll
      for(int u=0;u<8;u++){
        float gi=preact[(u   )*65+l]+b1L[u];
        float gf=preact[(8+u )*65+l]+b1L[8+u];
        float gg=preact[(16+u)*65+l]+b1L[16+u];
        float go=preact[(24+u)*65+l]+b1L[24+u];
        float c=sigf(gf)*c1s[u]+sigf(gi)*tanhf(gg);
        c1s[u]=c;
        float h=sigf(go)*tanhf(c);
        if(u<4) pk0.h[u]=(f16)h; else pk1.h[u-4]=(f16)h;
      }
      ast64(&GH1[p*8192+(q*64+l)*2  ], pk0.u);
      ast64(&GH1[p*8192+(q*64+l)*2+1], pk1.u);
    }
    GBAR();  // beta: h1(t) visible

    // ---- P3: DNC machinery for batch q ----
    if(tid<128){
      int g=tid>>1, hh=tid&1;
      U64H4 pv; pv.u=ald64(&GH1[p*8192+(g*64+q)*2+hh]);
      #pragma unroll
      for(int jj=0;jj<4;jj++){
        int k=g*8+hh*4+jj;
        float x=(float)pv.h[jj];
        x=fminf(fmaxf(x,-20.f),20.f);
        oc[k]=x;
        cat[(q*512+t)*576+k]=__float2bfloat16(x);
      }
    }
    __syncthreads();
    if(tid<405){
      int qq=tid/135, v=tid-qq*135;
      int k0=qq*171, k1=k0+171; if(k1>512)k1=512;
      float a=0.f;
      for(int k=k0;k<k1;k++) a += oc[k]*W_ifT[k*136+v];
      xpart[qq*136+v]=a;
    }
    __syncthreads();
    if(tid<135) xis[tid]=b_ifF[tid]+xpart[tid]+xpart[136+tid]+xpart[272+tid];
    __syncthreads();
    if(tid<5){
      int m=tid;
      float u=s_usage[m]+(1.f-s_usage[m])*s_wwp[m];
      float psi=1.f;
      #pragma unroll
      for(int r=0;r<4;r++) psi *= 1.f - sigf(xis[117+r])*s_rwp[r*5+m];
      u*=psi; s_usage[m]=u;
      float nm=0.f,dt=0.f,nk=0.f;
      #pragma unroll
      for(int w=0;w<16;w++){
        float mv=s_mem[m*16+w], kv=tanhf(xis[68+w]);
        nm+=mv*mv; dt+=mv*kv; nk+=kv*kv;
      }
      float sim=dt/((sqrtf(nm)+1e-6f)*(sqrtf(nk)+1e-6f));
      s_wl[m]=sim*splus(xis[84]);
    }
    __syncthreads();
    if(tid==0){
      float mx=-1e30f;
      for(int m=0;m<5;m++) mx=fmaxf(mx,s_wl[m]);
      float e[5]; float s=0.f;
      for(int m=0;m<5;m++){ e[m]=expf(s_wl[m]-mx); s+=e[m]; }
      float u[5]; int id[5];
      for(int m=0;m<5;m++){ u[m]=1e-6f+(1.f-1e-6f)*s_usage[m]; id[m]=m; }
      for(int i=1;i<5;i++){
        float uv=u[i]; int iv=id[i]; int j=i-1;
        while(j>=0&&u[j]>uv){u[j+1]=u[j];id[j+1]=id[j];j--;}
        u[j+1]=uv; id[j+1]=iv;
      }
      float alm[5]; float prod=1.f;
      for(int i=0;i<5;i++){ alm[id[i]]=(1.f-u[i])*prod; prod*=u[i]; }
      float ag=sigf(xis[121]), wgg=sigf(xis[122]);
      float wsum=0.f;
      for(int m=0;m<5;m++){
        float wcw=e[m]/s;
        float w_=wgg*(ag*alm[m]+(1.f-ag)*wcw);
        s_ww[m]=w_; wsum+=w_;
      }
      s_wsum=wsum;
    }
    __syncthreads();
    if(tid<80){
      int m=tid>>4,w=tid&15;
      float er=sigf(xis[85+w]), wvv=tanhf(xis[101+w]);
      float w_=s_ww[m];
      s_mem2[tid]=s_mem[tid]*(1.f-w_*er)+w_*wvv;
    } else if(tid>=128&&tid<153){
      int qq=tid-128; int i=qq/5, j=qq-5*i;
      s_link2[qq]=(i==j)?0.f:((1.f-s_ww[i]-s_ww[j])*s_link[qq]+s_ww[i]*s_prec[j]);
    } else if(tid>=160&&tid<165){
      int j=tid-160;
      s_prec2[j]=(1.f-s_wsum)*s_prec[j]+s_ww[j];
    }
    __syncthreads();
    if(tid<20){
      int r=tid/5,m=tid-5*(tid/5);
      float nm=0.f,dt=0.f,nk=0.f;
      #pragma unroll
      for(int w=0;w<16;w++){
        float mv=s_mem2[m*16+w], kv=tanhf(xis[r*16+w]);
        nm+=mv*mv; dt+=mv*kv; nk+=kv*kv;
      }
      float sim=dt/((sqrtf(nm)+1e-6f)*(sqrtf(nk)+1e-6f));
      s_rl[tid]=sim*splus(xis[64+r]);
    } else if(tid>=64&&tid<84){
      int qq=tid-64; int r=qq/5, i=qq-5*r;
      float a=0.f;
      #pragma unroll
      for(int j=0;j<5;j++) a+=s_link2[i*5+j]*s_rwp[r*5+j];
      s_fwd[r*5+i]=a;
    } else if(tid>=96&&tid<116){
      int qq=tid-96; int r=qq/5, j=qq-5*r;
      float a=0.f;
      #pragma unroll
      for(int i=0;i<5;i++) a+=s_link2[i*5+j]*s_rwp[r*5+i];
      s_bwd[r*5+j]=a;
    }
    __syncthreads();
    if(tid<20){
      int r=tid/5;
      float mx=-1e30f;
      for(int m=0;m<5;m++) mx=fmaxf(mx,s_rl[r*5+m]);
      float s=0.f;
      for(int m=0;m<5;m++) s+=expf(s_rl[r*5+m]-mx);
      float rcw=expf(s_rl[tid]-mx)/s;
      float q0=xis[123+3*r],q1=xis[124+3*r],q2=xis[125+3*r];
      float m3=fmaxf(q0,fmaxf(q1,q2));
      float e0=expf(q0-m3),e1=expf(q1-m3),e2=expf(q2-m3);
      float inv=1.f/(e0+e1+e2);
      s_rw[tid]=(e0*s_bwd[tid]+e1*s_fwd[tid]+e2*rcw)*inv;
    }
    __syncthreads();
    if(tid<64){
      int r=tid>>4,w=tid&15;
      float a=0.f;
      #pragma unroll
      for(int m=0;m<5;m++) a+=s_rw[tid>>4==r?r*5+m:0]*s_mem2[m*16+w];  // r*5+m
      // (written plainly below to avoid cleverness)
      a=0.f;
      #pragma unroll
      for(int m=0;m<5;m++) a+=s_rw[r*5+m]*s_mem2[m*16+w];
      rvbuf[tid]=a;
      cat[(q*512+t)*576+512+tid]=__float2bfloat16(a);
    } else if(tid>=128&&tid<208){ s_mem [tid-128]=s_mem2 [tid-128];
    } else if(tid>=208&&tid<233){ s_link[tid-208]=s_link2[tid-208];
    } else if(tid>=240&&tid<245){ s_prec[tid-240]=s_prec2[tid-240];
    } else if(tid>=256&&tid<276){ s_rwp [tid-256]=s_rw   [tid-256];
    } else if(tid>=288&&tid<293){ s_wwp [tid-288]=s_ww   [tid-288]; }
    __syncthreads();
    if(tid<32){
      U32H2 pk; pk.h[0]=(f16)rvbuf[2*tid]; pk.h[1]=(f16)rvbuf[2*tid+1];
      ast32(&((unsigned*)GLR)[p*2048 + ((tid>>2)*64+q)*4 + (tid&3)], pk.u);
    }
    GBAR();  // gamma: lr(t) visible
  }
#undef GBAR
}

// ---------------- final output GEMM (f32 out) ----------------
__global__ void __launch_bounds__(256) k_out(const bf16* __restrict__ cat,
                                             const float* __restrict__ Wc,
                                             const float* __restrict__ bc,
                                             float* __restrict__ outp){
  int t0=blockIdx.x*64, v0=blockIdx.y*64, b=blockIdx.z;
  __shared__ float As[64][33];
  __shared__ float Bs[32][65];
  int tid=threadIdx.x;
  int ti=tid>>4, vi=tid&15;
  float acc[4][4]={};
  for(int k0=0;k0<576;k0+=32){
    for(int i=tid;i<64*32;i+=256){
      int r=i>>5,k=i&31;
      As[r][k]=b2f(cat[(b*512+t0+r)*576+k0+k]);
    }
    for(int i=tid;i<64*32;i+=256){
      int v=i>>5,k=i&31;
      Bs[k][v]=Wc[(v0+v)*576+k0+k];
    }
    __syncthreads();
    #pragma unroll 8
    for(int kk=0;kk<32;kk++){
      float av[4],bv[4];
      #pragma unroll
      for(int x=0;x<4;x++) av[x]=As[ti*4+x][kk];
      #pragma unroll
      for(int y=0;y<4;y++) bv[y]=Bs[kk][vi*4+y];
      #pragma unroll
      for(int x=0;x<4;x++)
        #pragma unroll
        for(int y=0;y<4;y++) acc[x][y]+=av[x]*bv[y];
    }
    __syncthreads();
  }
  #pragma unroll
  for(int y=0;y<4;y++){
    int v=v0+vi*4+y;
    float bcv=bc[v];
    #pragma unroll
    for(int x=0;x<4;x++){
      int tt=t0+ti*4+x;
      outp[(b*256+v)*512+tt]=acc[x][y]+bcv;
    }
  }
}

extern "C" void kernel_launch(void* const* d_in, const int* in_sizes, int n_in,
                              void* d_out, int out_size, void* d_ws, size_t ws_size,
                              hipStream_t stream) {
  const int*  tokens = (const int*) d_in[0];
  const void* emb    = d_in[1];
  const void* Wi0    = d_in[2];
  const void* Wh0    = d_in[3];
  const void* b0     = d_in[4];
  const void* Wi1    = d_in[5];
  const void* Wh1    = d_in[6];
  const void* b1     = d_in[7];
  const void* W_if   = d_in[8];
  const void* b_if   = d_in[9];
  const void* W_out  = d_in[10];
  const void* b_out  = d_in[11];
  const void* W_fc   = d_in[12];
  const void* b_fc   = d_in[13];

  static const int expect[14] = {64*512, 256*512, 2048*576, 2048*512, 2048,
                                 2048*512, 2048*512, 2048, 135*512, 135,
                                 512*576, 512, 256*512, 256};
  bool ok = (n_in == 14);
  if(ok) for(int i=0;i<14;i++) if(in_sizes[i]!=expect[i]) ok=false;

  int*      flags = (int*)d_ws;                   // [0]=dtype flag, [1]=barrier ctr
  float*    embW  = (float*)d_ws + 64;            // 2048*256
  ushort_t* PA    = (ushort_t*)(embW + 524288);   // 1310720 f16
  ushort_t* PB    = PA + 1310720;                 // 2097152 f16
  float*    W_ifT = (float*)(PB + 2097152);       // 69632
  float*    b_ifF = W_ifT + 69632;                // 160
  float*    Wc    = b_ifF + 160;                  // 147456
  float*    bc    = Wc + 147456;                  // 256
  u64*      GH0   = (u64*)(bc + 256);             // 2*8192
  u64*      GH1   = GH0 + 16384;                  // 2*8192
  u64*      GLR   = GH1 + 16384;                  // 2*1024
  bf16*     cat   = (bf16*)(GLR + 2048);          // 64*512*576
  unsigned* ctr   = (unsigned*)(flags + 1);

  size_t need = 9783168ull + 278528ull + 37748736ull;   // = 47,810,432 B
  if(!ok || ws_size < need){
    hipMemsetAsync(d_out, 0, (size_t)out_size*4, stream);
    return;
  }

  k_detect<<<dim3(1), dim3(256), 0, stream>>>(emb, flags);
  k_embW<<<dim3(2048), dim3(256), 0, stream>>>(emb, Wi0, b0, flags, embW);
  k_wpkA<<<dim3(5120), dim3(256), 0, stream>>>(Wh0, Wi0, flags, PA);
  k_wpkB<<<dim3(8192), dim3(256), 0, stream>>>(Wi1, Wh1, flags, PB);
  k_wifT<<<dim3((135*512+255)/256), dim3(256), 0, stream>>>(W_if, b_if, flags, W_ifT, b_ifF);
  k_wc  <<<dim3(576),  dim3(256), 0, stream>>>(W_fc, W_out, b_out, b_fc, flags, Wc, bc);

  void* kargs[] = {
    (void*)&tokens, (void*)&b1, (void*)&flags,
    (void*)&embW, (void*)&PA, (void*)&PB,
    (void*)&W_ifT, (void*)&b_ifF,
    (void*)&GH0, (void*)&GH1, (void*)&GLR, (void*)&ctr,
    (void*)&cat
  };
  hipLaunchCooperativeKernel((const void*)k_dnc3, dim3(64), dim3(512), kargs, 0, stream);

  k_out<<<dim3(8,4,64), dim3(256), 0, stream>>>(cat, Wc, bc, (float*)d_out);
}

// Round 7
// 32976.443 us; speedup vs baseline: 5.7179x; 1.0415x over previous
//
#include <hip/hip_runtime.h>
#include <hip/hip_bf16.h>

typedef __hip_bfloat16 bf16;
typedef _Float16 f16;
typedef _Float16 f16x8 __attribute__((ext_vector_type(8)));
typedef float f32x4 __attribute__((ext_vector_type(4)));
typedef unsigned long long u64;
typedef unsigned short ushort_t;

__device__ __forceinline__ float b2f(bf16 x){ return __bfloat162float(x); }
__device__ __forceinline__ float sigf(float x){ return 1.f/(1.f+expf(-x)); }
__device__ __forceinline__ float splus(float x){ return fmaxf(x,0.f)+log1pf(expf(-fabsf(x))); }
__device__ __forceinline__ float ldf(const void* p, int i, int isf32){
  return isf32 ? ((const float*)p)[i] : __bfloat162float(((const bf16*)p)[i]);
}
// agent-scope coherent ops: serviced at the device coherence point (bypass per-XCD L2).
// Round-6 passing proves these are cross-XCD coherent with NO fences.
__device__ __forceinline__ void ast64(u64* p, u64 v){ __hip_atomic_store(p, v, __ATOMIC_RELAXED, __HIP_MEMORY_SCOPE_AGENT); }
__device__ __forceinline__ u64 ald64(u64* p){ return __hip_atomic_load(p, __ATOMIC_RELAXED, __HIP_MEMORY_SCOPE_AGENT); }
__device__ __forceinline__ void ast32(unsigned* p, unsigned v){ __hip_atomic_store(p, v, __ATOMIC_RELAXED, __HIP_MEMORY_SCOPE_AGENT); }

union U4H8 { uint4 u; f16x8 h; };
union U64H4 { u64 u; f16 h[4]; };
union U32H2 { unsigned u; f16 h[2]; };
union H16 { f16 h; ushort_t s; };

// ---------------- dtype detect + barrier-counter zero ----------------
__global__ void k_detect(const void* __restrict__ emb, int* __restrict__ flag){
  __shared__ float mx[256];
  int tid=threadIdx.x;
  float v = fabsf(__bfloat162float(((const bf16*)emb)[tid]));
  mx[tid]=v; __syncthreads();
  for(int s=128;s>0;s>>=1){ if(tid<s) mx[tid]=fmaxf(mx[tid],mx[tid+s]); __syncthreads(); }
  if(tid==0){ flag[0] = (mx[0]>1000.f) ? 1 : 0; flag[1] = 0; }  // flag[1] = barrier ctr
}

// ---------------- setup ----------------
// embW[row][v] = b0[row] + sum_k emb[v][k]*Wi0[row][k]
__global__ void k_embW(const void* __restrict__ emb, const void* __restrict__ Wi0,
                       const void* __restrict__ b0,
                       const int* __restrict__ flags, float* __restrict__ embW){
  int f=flags[0];
  int row = blockIdx.x;
  __shared__ float w[512];
  for(int k=threadIdx.x;k<512;k+=256) w[k]=ldf(Wi0,row*576+k,f);
  __syncthreads();
  int v = threadIdx.x;
  float acc=ldf(b0,row,f);
  #pragma unroll 4
  for(int k=0;k<512;k++) acc += ldf(emb,v*512+k,f)*w[k];
  embW[row*256+v]=acc;
}

// prepack phase-A weights into MFMA A-fragment order (f16)
__global__ void k_wpkA(const void* __restrict__ Wh0, const void* __restrict__ Wi0,
                       const int* __restrict__ flags, ushort_t* __restrict__ PA){
  int f=flags[0];
  int idx=blockIdx.x*256+threadIdx.x;
  if(idx>=1310720) return;
  int j=idx&7, lcl=(idx>>3)&63, fi=idx>>9;
  int c=fi%5, tq=fi/5, v=tq&7, q=tq>>3;
  int kh=v>>1, rt=v&1, m=lcl&15, quad=lcl>>4;
  int chunk=c*4+kh;
  int ri=rt*16+m, g=ri>>3, u=ri&7, row=(g<<9)+(q<<3)+u;
  int k=chunk*32+quad*8+j;
  float val=0.f;
  if(chunk<18) val = (k<512)? ldf(Wh0,row*512+k,f) : ldf(Wi0,row*576+k,f);
  H16 hh; hh.h=(f16)val; PA[idx]=hh.s;
}
__global__ void k_wpkB(const void* __restrict__ Wi1, const void* __restrict__ Wh1,
                       const int* __restrict__ flags, ushort_t* __restrict__ PB){
  int f=flags[0];
  int idx=blockIdx.x*256+threadIdx.x;
  if(idx>=2097152) return;
  int j=idx&7, lcl=(idx>>3)&63, c=(idx>>9)&7, v=(idx>>12)&7, q=idx>>15;
  int kh=v>>1, rt=v&1, m=lcl&15, quad=lcl>>4;
  int chunk=c*4+kh;
  int ri=rt*16+m, g=ri>>3, u=ri&7, row=(g<<9)+(q<<3)+u;
  int k=chunk*32+quad*8+j;
  float val = (k<512)? ldf(Wi1,row*512+k,f) : ldf(Wh1,row*512+k-512,f);
  H16 hh; hh.h=(f16)val; PB[idx]=hh.s;
}

__global__ void k_wifT(const void* __restrict__ W_if, const void* __restrict__ b_if,
                       const int* __restrict__ flags,
                       float* __restrict__ W_ifT, float* __restrict__ b_ifF){
  int f=flags[0];
  int idx=blockIdx.x*256+threadIdx.x;
  if(idx<135*512){ int v=idx/512, k=idx-v*512; W_ifT[k*136+v]=ldf(W_if,idx,f); }
  if(idx<135) b_ifF[idx]=ldf(b_if,idx,f);
}

__global__ void k_wc(const void* __restrict__ W_fc, const void* __restrict__ W_out,
                     const void* __restrict__ b_out, const void* __restrict__ b_fc,
                     const int* __restrict__ flags,
                     float* __restrict__ Wc, float* __restrict__ bc){
  int f=flags[0];
  int idx=blockIdx.x*256+threadIdx.x;
  int v=idx/576, j=idx-v*576;
  float acc=0.f;
  #pragma unroll 4
  for(int d=0;d<512;d++) acc += ldf(W_fc,v*512+d,f)*ldf(W_out,d*576+j,f);
  Wc[idx]=acc;
  if(j==0){
    float a=ldf(b_fc,v,f);
    for(int d=0;d<512;d++) a += ldf(W_fc,v*512+d,f)*ldf(b_out,d,f);
    bc[v]=a;
  }
}

// ---------------- cooperative recurrence: 64 wgs x 512 thr, row-partitioned, MFMA ----------------
__global__ void __launch_bounds__(512) k_dnc3(
    const int* __restrict__ tokens, const void* __restrict__ b1, const int* __restrict__ flags,
    const float* __restrict__ embW, const ushort_t* __restrict__ PA, const ushort_t* __restrict__ PB,
    const float* __restrict__ W_ifT, const float* __restrict__ b_ifF,
    u64* GH0, u64* GH1, u64* GLR, unsigned* ctr,
    bf16* __restrict__ cat)
{
  const int q   = blockIdx.x;
  const int tid = threadIdx.x;
  const int wv  = tid>>6, l = tid&63;
  const int lm  = l&15,  quad = l>>4;
  const int rt  = wv&1,  kh = wv>>1;
  const int f32i = flags[0];

  __shared__ u64  HBuf[2][2048];
  __shared__ float preact[32*65];
  __shared__ float oc[512];
  __shared__ float b1L[32];
  __shared__ float xis[136], xpart[3*136];
  __shared__ float s_mem[80], s_mem2[80], s_link[25], s_link2[25];
  __shared__ float s_prec[5], s_prec2[5], s_rwp[20], s_rw[20];
  __shared__ float s_wwp[5], s_ww[5], s_usage[5], s_wl[5];
  __shared__ float s_rl[20], s_fwd[20], s_bwd[20], s_wsum;
  __shared__ float rvbuf[64];

  // resident weight fragments
  f16x8 fa[5], fb[8];
  {
    const uint4* PAv=(const uint4*)PA;
    const uint4* PBv=(const uint4*)PB;
    #pragma unroll
    for(int c=0;c<5;c++){ U4H8 t4; t4.u = PAv[((q*8+wv)*5+c)*64 + l]; fa[c]=t4.h; }
    #pragma unroll
    for(int c=0;c<8;c++){ U4H8 t4; t4.u = PBv[((q*8+wv)*8+c)*64 + l]; fb[c]=t4.h; }
  }
  if(tid<32){ int g=tid>>3,u=tid&7; b1L[tid]=ldf(b1,(g<<9)+(q<<3)+u,f32i); }
  if(tid<80) s_mem[tid]=0.f;
  if(tid>=128&&tid<153) s_link[tid-128]=0.f;
  if(tid>=160&&tid<165) s_prec[tid-160]=0.f;
  if(tid>=192&&tid<212) s_rwp[tid-192]=0.f;
  if(tid>=224&&tid<229) s_wwp[tid-224]=0.f;
  if(tid>=256&&tid<261) s_usage[tid-256]=0.f;
  if(tid<128){ ast64(&GH0[8192 + (q*64+(tid>>1))*2 + (tid&1)], 0ull);
               ast64(&GH1[8192 + (q*64+(tid>>1))*2 + (tid&1)], 0ull); }
  if(tid<16){  ast64(&GLR[1024 + ((tid>>1)*64+q)*2 + (tid&1)], 0ull); }
  float c0s[8], c1s[8];
  #pragma unroll
  for(int u=0;u<8;u++){ c0s[u]=0.f; c1s[u]=0.f; }

  // ALL-RELAXED barrier. Correctness: __syncthreads drains vmcnt(0) for every
  // wave (compiler-inserted s_waitcnt before s_barrier), so all agent-scope
  // data stores are at the coherence point before tid0's arrival RMW lands
  // there. Consumers read via agent-scope loads (bypass L2) -> no inv needed.
  unsigned nb=0;
#define GBAR() do{ nb++; __syncthreads(); \
  if(tid==0){ __hip_atomic_fetch_add(ctr,1u,__ATOMIC_RELAXED,__HIP_MEMORY_SCOPE_AGENT); \
    while(__hip_atomic_load(ctr,__ATOMIC_RELAXED,__HIP_MEMORY_SCOPE_AGENT) < nb*64u) __builtin_amdgcn_s_sleep(1); } \
  __syncthreads(); }while(0)

  GBAR();   // init visible

  for(int t=0;t<512;t++){
    const int p=t&1, pm=p^1;
    // ---- phase A ----
    u64 ra[18];
    #pragma unroll
    for(int i=0;i<16;i++) ra[i]=ald64(&GH0[pm*8192 + tid + 512*i]);
    #pragma unroll
    for(int i=16;i<18;i++) ra[i]=ald64(&GLR[pm*1024 + tid + 512*(i-16)]);
    float em[4][8];
    if(wv==0){
      int tokb = tokens[l*512+t];
      #pragma unroll
      for(int g=0;g<4;g++)
        #pragma unroll
        for(int u=0;u<8;u++)
          em[g][u]=embW[((g<<9)+(q<<3)+u)*256 + tokb];
    }
    for(int i=tid;i<2080;i+=512) preact[i]=0.f;
    f32x4 acc[4];
    #pragma unroll
    for(int bt=0;bt<4;bt++) acc[bt]=(f32x4){0.f,0.f,0.f,0.f};
    #pragma unroll
    for(int blk=0;blk<5;blk++){
      int nreg=(blk<4)?4:2;
      #pragma unroll
      for(int jj=0;jj<4;jj++) if(jj<nreg) HBuf[blk&1][tid+512*jj]=ra[blk*4+jj];
      __syncthreads();
      if(blk<4 || kh<2){
        const f16x8* hb=(const f16x8*)(&HBuf[blk&1][0]);
        #pragma unroll
        for(int bt=0;bt<4;bt++){
          f16x8 bfr = hb[(kh*4+quad)*64 + bt*16 + lm];
          acc[bt]=__builtin_amdgcn_mfma_f32_16x16x32_f16(fa[blk],bfr,acc[bt],0,0,0);
        }
      }
    }
    #pragma unroll
    for(int bt=0;bt<4;bt++)
      #pragma unroll
      for(int r=0;r<4;r++)
        atomicAdd(&preact[(rt*16+quad*4+r)*65 + bt*16 + lm], acc[bt][r]);
    __syncthreads();
    if(wv==0){
      U64H4 pk0, pk1;
      #pragma unroll
      for(int u=0;u<8;u++){
        float gi=preact[(u   )*65+l]+em[0][u];
        float gf=preact[(8+u )*65+l]+em[1][u];
        float gg=preact[(16+u)*65+l]+em[2][u];
        float go=preact[(24+u)*65+l]+em[3][u];
        float c=sigf(gf)*c0s[u]+sigf(gi)*tanhf(gg);
        c0s[u]=c;
        float h=sigf(go)*tanhf(c);
        if(u<4) pk0.h[u]=(f16)h; else pk1.h[u-4]=(f16)h;
      }
      ast64(&GH0[p*8192+(q*64+l)*2  ], pk0.u);
      ast64(&GH0[p*8192+(q*64+l)*2+1], pk1.u);
    }
    GBAR();  // alpha: h0'(t) visible

    // ---- phase B ----
    u64 rb[32];
    #pragma unroll
    for(int i=0;i<16;i++) rb[i]=ald64(&GH0[p*8192 + tid + 512*i]);
    #pragma unroll
    for(int i=16;i<32;i++) rb[i]=ald64(&GH1[pm*8192 + tid + 512*(i-16)]);
    for(int i=tid;i<2080;i+=512) preact[i]=0.f;
    #pragma unroll
    for(int bt=0;bt<4;bt++) acc[bt]=(f32x4){0.f,0.f,0.f,0.f};
    #pragma unroll
    for(int blk=0;blk<8;blk++){
      #pragma unroll
      for(int jj=0;jj<4;jj++) HBuf[blk&1][tid+512*jj]=rb[blk*4+jj];
      __syncthreads();
      const f16x8* hb=(const f16x8*)(&HBuf[blk&1][0]);
      #pragma unroll
      for(int bt=0;bt<4;bt++){
        f16x8 bfr = hb[(kh*4+quad)*64 + bt*16 + lm];
        acc[bt]=__builtin_amdgcn_mfma_f32_16x16x32_f16(fb[blk],bfr,acc[bt],0,0,0);
      }
    }
    #pragma unroll
    for(int bt=0;bt<4;bt++)
      #pragma unroll
      for(int r=0;r<4;r++)
        atomicAdd(&preact[(rt*16+quad*4+r)*65 + bt*16 + lm], acc[bt][r]);
    __syncthreads();
    if(wv==0){
      U64H4 pk0, pk1;
      #pragma unroll
      for(int u=0;u<8;u++){
        float gi=preact[(u   )*65+l]+b1L[u];
        float gf=preact[(8+u )*65+l]+b1L[8+u];
        float gg=preact[(16+u)*65+l]+b1L[16+u];
        float go=preact[(24+u)*65+l]+b1L[24+u];
        float c=sigf(gf)*c1s[u]+sigf(gi)*tanhf(gg);
        c1s[u]=c;
        float h=sigf(go)*tanhf(c);
        if(u<4) pk0.h[u]=(f16)h; else pk1.h[u-4]=(f16)h;
      }
      ast64(&GH1[p*8192+(q*64+l)*2  ], pk0.u);
      ast64(&GH1[p*8192+(q*64+l)*2+1], pk1.u);
    }
    GBAR();  // beta: h1(t) visible

    // ---- P3: DNC machinery for batch q ----
    if(tid<128){
      int g=tid>>1, hh=tid&1;
      U64H4 pv; pv.u=ald64(&GH1[p*8192+(g*64+q)*2+hh]);
      #pragma unroll
      for(int jj=0;jj<4;jj++){
        int k=g*8+hh*4+jj;
        float x=(float)pv.h[jj];
        x=fminf(fmaxf(x,-20.f),20.f);
        oc[k]=x;
        cat[(q*512+t)*576+k]=__float2bfloat16(x);
      }
    }
    __syncthreads();
    if(tid<405){
      int qq=tid/135, v=tid-qq*135;
      int k0=qq*171, k1=k0+171; if(k1>512)k1=512;
      float a=0.f;
      for(int k=k0;k<k1;k++) a += oc[k]*W_ifT[k*136+v];
      xpart[qq*136+v]=a;
    }
    __syncthreads();
    if(tid<135) xis[tid]=b_ifF[tid]+xpart[tid]+xpart[136+tid]+xpart[272+tid];
    __syncthreads();
    if(tid<5){
      int m=tid;
      float u=s_usage[m]+(1.f-s_usage[m])*s_wwp[m];
      float psi=1.f;
      #pragma unroll
      for(int r=0;r<4;r++) psi *= 1.f - sigf(xis[117+r])*s_rwp[r*5+m];
      u*=psi; s_usage[m]=u;
      float nm=0.f,dt=0.f,nk=0.f;
      #pragma unroll
      for(int w=0;w<16;w++){
        float mv=s_mem[m*16+w], kv=tanhf(xis[68+w]);
        nm+=mv*mv; dt+=mv*kv; nk+=kv*kv;
      }
      float sim=dt/((sqrtf(nm)+1e-6f)*(sqrtf(nk)+1e-6f));
      s_wl[m]=sim*splus(xis[84]);
    }
    __syncthreads();
    if(tid==0){
      float mx=-1e30f;
      for(int m=0;m<5;m++) mx=fmaxf(mx,s_wl[m]);
      float e[5]; float s=0.f;
      for(int m=0;m<5;m++){ e[m]=expf(s_wl[m]-mx); s+=e[m]; }
      float u[5]; int id[5];
      for(int m=0;m<5;m++){ u[m]=1e-6f+(1.f-1e-6f)*s_usage[m]; id[m]=m; }
      for(int i=1;i<5;i++){
        float uv=u[i]; int iv=id[i]; int j=i-1;
        while(j>=0&&u[j]>uv){u[j+1]=u[j];id[j+1]=id[j];j--;}
        u[j+1]=uv; id[j+1]=iv;
      }
      float alm[5]; float prod=1.f;
      for(int i=0;i<5;i++){ alm[id[i]]=(1.f-u[i])*prod; prod*=u[i]; }
      float ag=sigf(xis[121]), wgg=sigf(xis[122]);
      float wsum=0.f;
      for(int m=0;m<5;m++){
        float wcw=e[m]/s;
        float w_=wgg*(ag*alm[m]+(1.f-ag)*wcw);
        s_ww[m]=w_; wsum+=w_;
      }
      s_wsum=wsum;
    }
    __syncthreads();
    if(tid<80){
      int m=tid>>4,w=tid&15;
      float er=sigf(xis[85+w]), wvv=tanhf(xis[101+w]);
      float w_=s_ww[m];
      s_mem2[tid]=s_mem[tid]*(1.f-w_*er)+w_*wvv;
    } else if(tid>=128&&tid<153){
      int qq=tid-128; int i=qq/5, j=qq-5*i;
      s_link2[qq]=(i==j)?0.f:((1.f-s_ww[i]-s_ww[j])*s_link[qq]+s_ww[i]*s_prec[j]);
    } else if(tid>=160&&tid<165){
      int j=tid-160;
      s_prec2[j]=(1.f-s_wsum)*s_prec[j]+s_ww[j];
    }
    __syncthreads();
    if(tid<20){
      int r=tid/5,m=tid-5*(tid/5);
      float nm=0.f,dt=0.f,nk=0.f;
      #pragma unroll
      for(int w=0;w<16;w++){
        float mv=s_mem2[m*16+w], kv=tanhf(xis[r*16+w]);
        nm+=mv*mv; dt+=mv*kv; nk+=kv*kv;
      }
      float sim=dt/((sqrtf(nm)+1e-6f)*(sqrtf(nk)+1e-6f));
      s_rl[tid]=sim*splus(xis[64+r]);
    } else if(tid>=64&&tid<84){
      int qq=tid-64; int r=qq/5, i=qq-5*r;
      float a=0.f;
      #pragma unroll
      for(int j=0;j<5;j++) a+=s_link2[i*5+j]*s_rwp[r*5+j];
      s_fwd[r*5+i]=a;
    } else if(tid>=96&&tid<116){
      int qq=tid-96; int r=qq/5, j=qq-5*r;
      float a=0.f;
      #pragma unroll
      for(int i=0;i<5;i++) a+=s_link2[i*5+j]*s_rwp[r*5+i];
      s_bwd[r*5+j]=a;
    }
    __syncthreads();
    if(tid<20){
      int r=tid/5;
      float mx=-1e30f;
      for(int m=0;m<5;m++) mx=fmaxf(mx,s_rl[r*5+m]);
      float s=0.f;
      for(int m=0;m<5;m++) s+=expf(s_rl[r*5+m]-mx);
      float rcw=expf(s_rl[tid]-mx)/s;
      float q0=xis[123+3*r],q1=xis[124+3*r],q2=xis[125+3*r];
      float m3=fmaxf(q0,fmaxf(q1,q2));
      float e0=expf(q0-m3),e1=expf(q1-m3),e2=expf(q2-m3);
      float inv=1.f/(e0+e1+e2);
      s_rw[tid]=(e0*s_bwd[tid]+e1*s_fwd[tid]+e2*rcw)*inv;
    }
    __syncthreads();
    if(tid<64){
      int r=tid>>4,w=tid&15;
      float a=0.f;
      #pragma unroll
      for(int m=0;m<5;m++) a+=s_rw[r*5+m]*s_mem2[m*16+w];
      rvbuf[tid]=a;
      cat[(q*512+t)*576+512+tid]=__float2bfloat16(a);
    } else if(tid>=128&&tid<208){ s_mem [tid-128]=s_mem2 [tid-128];
    } else if(tid>=208&&tid<233){ s_link[tid-208]=s_link2[tid-208];
    } else if(tid>=240&&tid<245){ s_prec[tid-240]=s_prec2[tid-240];
    } else if(tid>=256&&tid<276){ s_rwp [tid-256]=s_rw   [tid-256];
    } else if(tid>=288&&tid<293){ s_wwp [tid-288]=s_ww   [tid-288]; }
    __syncthreads();
    if(tid<32){
      U32H2 pk; pk.h[0]=(f16)rvbuf[2*tid]; pk.h[1]=(f16)rvbuf[2*tid+1];
      ast32(&((unsigned*)GLR)[p*2048 + ((tid>>2)*64+q)*4 + (tid&3)], pk.u);
    }
    GBAR();  // gamma: lr(t) visible
  }
#undef GBAR
}

// ---------------- final output GEMM (f32 out) ----------------
__global__ void __launch_bounds__(256) k_out(const bf16* __restrict__ cat,
                                             const float* __restrict__ Wc,
                                             const float* __restrict__ bc,
                                             float* __restrict__ outp){
  int t0=blockIdx.x*64, v0=blockIdx.y*64, b=blockIdx.z;
  __shared__ float As[64][33];
  __shared__ float Bs[32][65];
  int tid=threadIdx.x;
  int ti=tid>>4, vi=tid&15;
  float acc[4][4]={};
  for(int k0=0;k0<576;k0+=32){
    for(int i=tid;i<64*32;i+=256){
      int r=i>>5,k=i&31;
      As[r][k]=b2f(cat[(b*512+t0+r)*576+k0+k]);
    }
    for(int i=tid;i<64*32;i+=256){
      int v=i>>5,k=i&31;
      Bs[k][v]=Wc[(v0+v)*576+k0+k];
    }
    __syncthreads();
    #pragma unroll 8
    for(int kk=0;kk<32;kk++){
      float av[4],bv[4];
      #pragma unroll
      for(int x=0;x<4;x++) av[x]=As[ti*4+x][kk];
      #pragma unroll
      for(int y=0;y<4;y++) bv[y]=Bs[kk][vi*4+y];
      #pragma unroll
      for(int x=0;x<4;x++)
        #pragma unroll
        for(int y=0;y<4;y++) acc[x][y]+=av[x]*bv[y];
    }
    __syncthreads();
  }
  #pragma unroll
  for(int y=0;y<4;y++){
    int v=v0+vi*4+y;
    float bcv=bc[v];
    #pragma unroll
    for(int x=0;x<4;x++){
      int tt=t0+ti*4+x;
      outp[(b*256+v)*512+tt]=acc[x][y]+bcv;
    }
  }
}

extern "C" void kernel_launch(void* const* d_in, const int* in_sizes, int n_in,
                              void* d_out, int out_size, void* d_ws, size_t ws_size,
                              hipStream_t stream) {
  const int*  tokens = (const int*) d_in[0];
  const void* emb    = d_in[1];
  const void* Wi0    = d_in[2];
  const void* Wh0    = d_in[3];
  const void* b0     = d_in[4];
  const void* Wi1    = d_in[5];
  const void* Wh1    = d_in[6];
  const void* b1     = d_in[7];
  const void* W_if   = d_in[8];
  const void* b_if   = d_in[9];
  const void* W_out  = d_in[10];
  const void* b_out  = d_in[11];
  const void* W_fc   = d_in[12];
  const void* b_fc   = d_in[13];

  static const int expect[14] = {64*512, 256*512, 2048*576, 2048*512, 2048,
                                 2048*512, 2048*512, 2048, 135*512, 135,
                                 512*576, 512, 256*512, 256};
  bool ok = (n_in == 14);
  if(ok) for(int i=0;i<14;i++) if(in_sizes[i]!=expect[i]) ok=false;

  int*      flags = (int*)d_ws;                   // [0]=dtype flag, [1]=barrier ctr
  float*    embW  = (float*)d_ws + 64;            // 2048*256
  ushort_t* PA    = (ushort_t*)(embW + 524288);   // 1310720 f16
  ushort_t* PB    = PA + 1310720;                 // 2097152 f16
  float*    W_ifT = (float*)(PB + 2097152);       // 69632
  float*    b_ifF = W_ifT + 69632;                // 160
  float*    Wc    = b_ifF + 160;                  // 147456
  float*    bc    = Wc + 147456;                  // 256
  u64*      GH0   = (u64*)(bc + 256);             // 2*8192
  u64*      GH1   = GH0 + 16384;                  // 2*8192
  u64*      GLR   = GH1 + 16384;                  // 2*1024
  bf16*     cat   = (bf16*)(GLR + 2048);          // 64*512*576
  unsigned* ctr   = (unsigned*)(flags + 1);

  size_t need = 9783168ull + 278528ull + 37748736ull;   // = 47,810,432 B
  if(!ok || ws_size < need){
    hipMemsetAsync(d_out, 0, (size_t)out_size*4, stream);
    return;
  }

  k_detect<<<dim3(1), dim3(256), 0, stream>>>(emb, flags);
  k_embW<<<dim3(2048), dim3(256), 0, stream>>>(emb, Wi0, b0, flags, embW);
  k_wpkA<<<dim3(5120), dim3(256), 0, stream>>>(Wh0, Wi0, flags, PA);
  k_wpkB<<<dim3(8192), dim3(256), 0, stream>>>(Wi1, Wh1, flags, PB);
  k_wifT<<<dim3((135*512+255)/256), dim3(256), 0, stream>>>(W_if, b_if, flags, W_ifT, b_ifF);
  k_wc  <<<dim3(576),  dim3(256), 0, stream>>>(W_fc, W_out, b_out, b_fc, flags, Wc, bc);

  void* kargs[] = {
    (void*)&tokens, (void*)&b1, (void*)&flags,
    (void*)&embW, (void*)&PA, (void*)&PB,
    (void*)&W_ifT, (void*)&b_ifF,
    (void*)&GH0, (void*)&GH1, (void*)&GLR, (void*)&ctr,
    (void*)&cat
  };
  hipLaunchCooperativeKernel((const void*)k_dnc3, dim3(64), dim3(512), kargs, 0, stream);

  k_out<<<dim3(8,4,64), dim3(256), 0, stream>>>(cat, Wc, bc, (float*)d_out);
}